// Round 1
// baseline (7437.605 us; speedup 1.0000x reference)
//
#include <hip/hip_runtime.h>
#include <math.h>

#define DIMN 1536
#define NHEAD 12
#define HDIM 128
#define SLEN 2048
#define EPSV 1e-6f

// ---------------------------------------------------------------------------
// GEMM: Y[m,n] = bias[n] + sum_k A[m,k] * W[n,k]   (A: MxK row-major, W: NxK)
// 64x64 tile per block, 256 threads, 4x4 per thread, K-tile 32.
// ---------------------------------------------------------------------------
__global__ __launch_bounds__(256)
void gemm_xwt(const float* __restrict__ A, const float* __restrict__ W,
              const float* __restrict__ bias, float* __restrict__ Y,
              int M, int N, int K)
{
    __shared__ __attribute__((aligned(16))) float As[32][64];
    __shared__ __attribute__((aligned(16))) float Bs[32][64];

    const int tid = threadIdx.x;
    const int tx = tid & 15;          // n-direction
    const int ty = tid >> 4;          // m-direction
    const int m0 = blockIdx.y * 64;
    const int n0 = blockIdx.x * 64;

    // loader mapping: row within tile, 8-consecutive-k chunk
    const int lr = tid >> 2;          // 0..63
    const int lc = (tid & 3) * 8;     // 0,8,16,24

    float c[4][4] = {};

    for (int kt = 0; kt < K; kt += 32) {
        const float* ap = A + (size_t)(m0 + lr) * K + kt + lc;
        const float* bp = W + (size_t)(n0 + lr) * K + kt + lc;
        float4 a0 = *(const float4*)ap;
        float4 a1 = *(const float4*)(ap + 4);
        float4 b0 = *(const float4*)bp;
        float4 b1 = *(const float4*)(bp + 4);

        __syncthreads();   // protect previous iteration's LDS reads
        As[lc + 0][lr] = a0.x; As[lc + 1][lr] = a0.y;
        As[lc + 2][lr] = a0.z; As[lc + 3][lr] = a0.w;
        As[lc + 4][lr] = a1.x; As[lc + 5][lr] = a1.y;
        As[lc + 6][lr] = a1.z; As[lc + 7][lr] = a1.w;
        Bs[lc + 0][lr] = b0.x; Bs[lc + 1][lr] = b0.y;
        Bs[lc + 2][lr] = b0.z; Bs[lc + 3][lr] = b0.w;
        Bs[lc + 4][lr] = b1.x; Bs[lc + 5][lr] = b1.y;
        Bs[lc + 6][lr] = b1.z; Bs[lc + 7][lr] = b1.w;
        __syncthreads();

        #pragma unroll
        for (int kk = 0; kk < 32; ++kk) {
            float4 av = *(const float4*)&As[kk][ty * 4];
            float4 bv = *(const float4*)&Bs[kk][tx * 4];
            float a[4] = {av.x, av.y, av.z, av.w};
            float b[4] = {bv.x, bv.y, bv.z, bv.w};
            #pragma unroll
            for (int i = 0; i < 4; ++i)
                #pragma unroll
                for (int j = 0; j < 4; ++j)
                    c[i][j] = fmaf(a[i], b[j], c[i][j]);
        }
    }

    const float4 bb = *(const float4*)(bias + n0 + tx * 4);
    #pragma unroll
    for (int i = 0; i < 4; ++i) {
        float4 o;
        o.x = c[i][0] + bb.x;
        o.y = c[i][1] + bb.y;
        o.z = c[i][2] + bb.z;
        o.w = c[i][3] + bb.w;
        *(float4*)&Y[(size_t)(m0 + ty * 4 + i) * N + n0 + tx * 4] = o;
    }
}

// ---------------------------------------------------------------------------
// Fused RMSNorm (over DIM) + RoPE (per head, 64 pairs). In-place on buf.
// ang(s,d): d<22 -> freqs[f_idx,d]; 22<=d<43 -> freqs[h_idx,d]; d>=43 -> freqs[w_idx,d]
// ---------------------------------------------------------------------------
__global__ __launch_bounds__(256)
void rms_rope(float* __restrict__ buf, const float* __restrict__ g,
              const float* __restrict__ freqs, const int* __restrict__ grid_sizes)
{
    const int s = blockIdx.x;
    const int tid = threadIdx.x;
    float* row = buf + (size_t)s * DIMN;

    float ss = 0.f;
    for (int i = tid; i < DIMN; i += 256) { float v = row[i]; ss += v * v; }
    #pragma unroll
    for (int off = 32; off; off >>= 1) ss += __shfl_down(ss, off, 64);

    __shared__ float red[4];
    __shared__ float s_scale;
    if ((tid & 63) == 0) red[tid >> 6] = ss;
    __syncthreads();
    if (tid == 0) {
        float t = red[0] + red[1] + red[2] + red[3];
        s_scale = rsqrtf(t / (float)DIMN + EPSV);
    }
    __syncthreads();
    const float scale = s_scale;

    const int h = grid_sizes[1], w = grid_sizes[2];
    const int fi = s / (h * w);
    const int hi = (s / w) % h;
    const int wi = s % w;

    for (int p = tid; p < NHEAD * 64; p += 256) {
        const int n = p >> 6;
        const int d = p & 63;
        const int idx = (d < 22) ? fi : ((d < 43) ? hi : wi);
        const float ang = freqs[idx * 64 + d];
        const float cs = cosf(ang), sn = sinf(ang);
        const int base = n * HDIM + 2 * d;
        const float v0 = row[base] * scale * g[base];
        const float v1 = row[base + 1] * scale * g[base + 1];
        row[base]     = v0 * cs - v1 * sn;
        row[base + 1] = v0 * sn + v1 * cs;
    }
}

// ---------------------------------------------------------------------------
// Attention: one block per (q-row s, head n). Scores in LDS, 2-pass softmax.
// ---------------------------------------------------------------------------
__global__ __launch_bounds__(256)
void attention(const float* __restrict__ Q, const float* __restrict__ K,
               const float* __restrict__ V, float* __restrict__ O,
               const int* __restrict__ seq_lens)
{
    __shared__ float sc[SLEN];                                   // 8 KB
    __shared__ __attribute__((aligned(16))) float qrow[HDIM];
    __shared__ float red[4];
    __shared__ float m_sh, l_sh;
    __shared__ float part[128];

    const int s = blockIdx.x;
    const int n = blockIdx.y;
    const int tid = threadIdx.x;
    const int slen = seq_lens[0];

    if (tid < HDIM) qrow[tid] = Q[(size_t)s * DIMN + n * HDIM + tid];
    __syncthreads();

    const float scale = 0.08838834764831845f;   // 1/sqrt(128)

    float myscores[8];
    float mymax = -3.402823466e38f;
    #pragma unroll
    for (int i = 0; i < 8; ++i) {
        const int j = tid + i * 256;
        float acc = 0.f;
        const float* kp = K + (size_t)j * DIMN + n * HDIM;
        #pragma unroll
        for (int d = 0; d < HDIM; d += 4) {
            float4 kv = *(const float4*)(kp + d);
            float4 qv = *(const float4*)(qrow + d);
            acc = fmaf(qv.x, kv.x, acc);
            acc = fmaf(qv.y, kv.y, acc);
            acc = fmaf(qv.z, kv.z, acc);
            acc = fmaf(qv.w, kv.w, acc);
        }
        acc *= scale;
        if (j >= slen) acc = -3.402823466e38f;
        myscores[i] = acc;
        mymax = fmaxf(mymax, acc);
    }

    #pragma unroll
    for (int off = 32; off; off >>= 1) mymax = fmaxf(mymax, __shfl_down(mymax, off, 64));
    if ((tid & 63) == 0) red[tid >> 6] = mymax;
    __syncthreads();
    if (tid == 0) m_sh = fmaxf(fmaxf(red[0], red[1]), fmaxf(red[2], red[3]));
    __syncthreads();
    const float m = m_sh;

    float mysum = 0.f;
    #pragma unroll
    for (int i = 0; i < 8; ++i) {
        float e = expf(myscores[i] - m);
        sc[tid + i * 256] = e;
        mysum += e;
    }
    #pragma unroll
    for (int off = 32; off; off >>= 1) mysum += __shfl_down(mysum, off, 64);
    if ((tid & 63) == 0) red[tid >> 6] = mysum;
    __syncthreads();
    if (tid == 0) l_sh = red[0] + red[1] + red[2] + red[3];
    __syncthreads();
    const float inv = 1.0f / l_sh;

    // phase 3: out[d] = sum_j p[j] * V[j, n*HD + d]; split j across two halves
    const int d = tid & 127;
    const int half = tid >> 7;
    float acc = 0.f;
    const float* vp = V + (size_t)half * 1024 * DIMN + n * HDIM + d;
    const float* scp = sc + half * 1024;
    for (int j = 0; j < 1024; ++j)
        acc = fmaf(scp[j], vp[(size_t)j * DIMN], acc);

    if (half == 1) part[d] = acc;
    __syncthreads();
    if (half == 0)
        O[(size_t)s * DIMN + n * HDIM + d] = (acc + part[d]) * inv;
}

// ---------------------------------------------------------------------------
extern "C" void kernel_launch(void* const* d_in, const int* in_sizes, int n_in,
                              void* d_out, int out_size, void* d_ws, size_t ws_size,
                              hipStream_t stream)
{
    const float* x     = (const float*)d_in[0];
    const float* freqs = (const float*)d_in[1];
    const float* wq    = (const float*)d_in[2];
    const float* bq    = (const float*)d_in[3];
    const float* wk    = (const float*)d_in[4];
    const float* bk    = (const float*)d_in[5];
    const float* wv    = (const float*)d_in[6];
    const float* bv    = (const float*)d_in[7];
    const float* wo    = (const float*)d_in[8];
    const float* bo    = (const float*)d_in[9];
    const float* gq    = (const float*)d_in[10];
    const float* gk    = (const float*)d_in[11];
    const int* seq_lens   = (const int*)d_in[12];
    const int* grid_sizes = (const int*)d_in[13];
    float* out = (float*)d_out;

    const size_t NELEM = (size_t)SLEN * DIMN;
    float* qbuf = (float*)d_ws;
    float* kbuf = qbuf + NELEM;
    float* vbuf = kbuf + NELEM;
    float* obuf = vbuf + NELEM;

    dim3 gblk(DIMN / 64, SLEN / 64);
    gemm_xwt<<<gblk, 256, 0, stream>>>(x, wq, bq, qbuf, SLEN, DIMN, DIMN);
    gemm_xwt<<<gblk, 256, 0, stream>>>(x, wk, bk, kbuf, SLEN, DIMN, DIMN);
    gemm_xwt<<<gblk, 256, 0, stream>>>(x, wv, bv, vbuf, SLEN, DIMN, DIMN);

    rms_rope<<<SLEN, 256, 0, stream>>>(qbuf, gq, freqs, grid_sizes);
    rms_rope<<<SLEN, 256, 0, stream>>>(kbuf, gk, freqs, grid_sizes);

    attention<<<dim3(SLEN, NHEAD), 256, 0, stream>>>(qbuf, kbuf, vbuf, obuf, seq_lens);

    gemm_xwt<<<gblk, 256, 0, stream>>>(obuf, wo, bo, out, SLEN, DIMN, DIMN);
}

// Round 2
// 1262.569 us; speedup vs baseline: 5.8909x; 5.8909x over previous
//
#include <hip/hip_runtime.h>
#include <math.h>

#define DIMN 1536
#define NHEAD 12
#define HDIM 128
#define SLEN 2048
#define EPSV 1e-6f

// ---------------------------------------------------------------------------
// GEMM: Y[m,n] = bias[n] + sum_k A[m,k] * W[n,k]   (A: MxK row-major, W: NxK)
// 64x64 tile per block, 256 threads, 4x4 per thread, K-tile 32.
// ---------------------------------------------------------------------------
__global__ __launch_bounds__(256)
void gemm_xwt(const float* __restrict__ A, const float* __restrict__ W,
              const float* __restrict__ bias, float* __restrict__ Y,
              int M, int N, int K)
{
    __shared__ __attribute__((aligned(16))) float As[32][64];
    __shared__ __attribute__((aligned(16))) float Bs[32][64];

    const int tid = threadIdx.x;
    const int tx = tid & 15;          // n-direction
    const int ty = tid >> 4;          // m-direction
    const int m0 = blockIdx.y * 64;
    const int n0 = blockIdx.x * 64;

    const int lr = tid >> 2;          // 0..63
    const int lc = (tid & 3) * 8;     // 0,8,16,24

    float c[4][4] = {};

    for (int kt = 0; kt < K; kt += 32) {
        const float* ap = A + (size_t)(m0 + lr) * K + kt + lc;
        const float* bp = W + (size_t)(n0 + lr) * K + kt + lc;
        float4 a0 = *(const float4*)ap;
        float4 a1 = *(const float4*)(ap + 4);
        float4 b0 = *(const float4*)bp;
        float4 b1 = *(const float4*)(bp + 4);

        __syncthreads();
        As[lc + 0][lr] = a0.x; As[lc + 1][lr] = a0.y;
        As[lc + 2][lr] = a0.z; As[lc + 3][lr] = a0.w;
        As[lc + 4][lr] = a1.x; As[lc + 5][lr] = a1.y;
        As[lc + 6][lr] = a1.z; As[lc + 7][lr] = a1.w;
        Bs[lc + 0][lr] = b0.x; Bs[lc + 1][lr] = b0.y;
        Bs[lc + 2][lr] = b0.z; Bs[lc + 3][lr] = b0.w;
        Bs[lc + 4][lr] = b1.x; Bs[lc + 5][lr] = b1.y;
        Bs[lc + 6][lr] = b1.z; Bs[lc + 7][lr] = b1.w;
        __syncthreads();

        #pragma unroll
        for (int kk = 0; kk < 32; ++kk) {
            float4 av = *(const float4*)&As[kk][ty * 4];
            float4 bv = *(const float4*)&Bs[kk][tx * 4];
            float a[4] = {av.x, av.y, av.z, av.w};
            float b[4] = {bv.x, bv.y, bv.z, bv.w};
            #pragma unroll
            for (int i = 0; i < 4; ++i)
                #pragma unroll
                for (int j = 0; j < 4; ++j)
                    c[i][j] = fmaf(a[i], b[j], c[i][j]);
        }
    }

    const float4 bb = *(const float4*)(bias + n0 + tx * 4);
    #pragma unroll
    for (int i = 0; i < 4; ++i) {
        float4 o;
        o.x = c[i][0] + bb.x;
        o.y = c[i][1] + bb.y;
        o.z = c[i][2] + bb.z;
        o.w = c[i][3] + bb.w;
        *(float4*)&Y[(size_t)(m0 + ty * 4 + i) * N + n0 + tx * 4] = o;
    }
}

// ---------------------------------------------------------------------------
// Fused RMSNorm + RoPE, in-place.
// ---------------------------------------------------------------------------
__global__ __launch_bounds__(256)
void rms_rope(float* __restrict__ buf, const float* __restrict__ g,
              const float* __restrict__ freqs, const int* __restrict__ grid_sizes)
{
    const int s = blockIdx.x;
    const int tid = threadIdx.x;
    float* row = buf + (size_t)s * DIMN;

    float ss = 0.f;
    for (int i = tid; i < DIMN; i += 256) { float v = row[i]; ss += v * v; }
    #pragma unroll
    for (int off = 32; off; off >>= 1) ss += __shfl_down(ss, off, 64);

    __shared__ float red[4];
    __shared__ float s_scale;
    if ((tid & 63) == 0) red[tid >> 6] = ss;
    __syncthreads();
    if (tid == 0) {
        float t = red[0] + red[1] + red[2] + red[3];
        s_scale = rsqrtf(t / (float)DIMN + EPSV);
    }
    __syncthreads();
    const float scale = s_scale;

    const int h = grid_sizes[1], w = grid_sizes[2];
    const int fi = s / (h * w);
    const int hi = (s / w) % h;
    const int wi = s % w;

    for (int p = tid; p < NHEAD * 64; p += 256) {
        const int n = p >> 6;
        const int d = p & 63;
        const int idx = (d < 22) ? fi : ((d < 43) ? hi : wi);
        const float ang = freqs[idx * 64 + d];
        const float cs = cosf(ang), sn = sinf(ang);
        const int base = n * HDIM + 2 * d;
        const float v0 = row[base] * scale * g[base];
        const float v1 = row[base + 1] * scale * g[base + 1];
        row[base]     = v0 * cs - v1 * sn;
        row[base + 1] = v0 * sn + v1 * cs;
    }
}

// ---------------------------------------------------------------------------
// Flash-style attention: one block per (64-row q-tile, head). 256 threads.
// K/V staged in 64-row LDS tiles; online softmax; register-blocked GEMMs.
// LDS ~118 KB -> 1 block/CU. 384 blocks.
// ---------------------------------------------------------------------------
__global__ __launch_bounds__(256)
void attention(const float* __restrict__ Q, const float* __restrict__ K,
               const float* __restrict__ V, float* __restrict__ O,
               const int* __restrict__ seq_lens)
{
    __shared__ __attribute__((aligned(16))) float Qs[128][68];  // [d][r], Q*scale
    __shared__ __attribute__((aligned(16))) float Ks[128][68];  // [d][j]
    __shared__ __attribute__((aligned(16))) float Vs[64][132];  // [j][d]
    __shared__ __attribute__((aligned(16))) float Ps[64][68];   // [j][r]

    const int tid = threadIdx.x;
    const int head = blockIdx.y;
    const int q0 = blockIdx.x * 64;
    const int slen = seq_lens[0];
    const int tx = tid & 15, ty = tid >> 4;
    const int lr = tid >> 2;            // tile row 0..63
    const int lq = (tid & 3) * 4;       // d-subchunk base

    const float scale = 0.08838834764831845f;  // 1/sqrt(128)

    {   // stage Q transposed (once), folding in the softmax scale
        const float* qp = Q + (size_t)(q0 + lr) * DIMN + head * HDIM;
        #pragma unroll
        for (int k = 0; k < 8; ++k) {
            const int d = lq + k * 16;
            float4 t = *(const float4*)(qp + d);
            Qs[d + 0][lr] = t.x * scale;
            Qs[d + 1][lr] = t.y * scale;
            Qs[d + 2][lr] = t.z * scale;
            Qs[d + 3][lr] = t.w * scale;
        }
    }

    float out[4][8] = {};
    float m_r[4] = {-1e30f, -1e30f, -1e30f, -1e30f};
    float l_r[4] = {0.f, 0.f, 0.f, 0.f};

    for (int kt = 0; kt < SLEN; kt += 64) {
        __syncthreads();   // prev iteration's PV reads of Vs/Ps done
        {
            const float* kp = K + (size_t)(kt + lr) * DIMN + head * HDIM;
            const float* vp = V + (size_t)(kt + lr) * DIMN + head * HDIM;
            #pragma unroll
            for (int k = 0; k < 8; ++k) {
                const int d = lq + k * 16;
                float4 t = *(const float4*)(kp + d);
                Ks[d + 0][lr] = t.x; Ks[d + 1][lr] = t.y;
                Ks[d + 2][lr] = t.z; Ks[d + 3][lr] = t.w;
                float4 v = *(const float4*)(vp + d);
                *(float4*)&Vs[lr][d] = v;
            }
        }
        __syncthreads();

        // S-tile 64x64: thread (tx,ty) computes rows 4ty..+3, cols 4tx..+3
        float s[4][4] = {};
        #pragma unroll 8
        for (int kk = 0; kk < 128; ++kk) {
            float4 a = *(const float4*)&Qs[kk][ty * 4];
            float4 b = *(const float4*)&Ks[kk][tx * 4];
            float av[4] = {a.x, a.y, a.z, a.w};
            float bv[4] = {b.x, b.y, b.z, b.w};
            #pragma unroll
            for (int i = 0; i < 4; ++i)
                #pragma unroll
                for (int jj = 0; jj < 4; ++jj)
                    s[i][jj] = fmaf(av[i], bv[jj], s[i][jj]);
        }

        #pragma unroll
        for (int jj = 0; jj < 4; ++jj) {
            if (kt + tx * 4 + jj >= slen) {
                #pragma unroll
                for (int i = 0; i < 4; ++i) s[i][jj] = -1e30f;
            }
        }

        // online softmax per row (reduce across the 16 tx lanes of this ty)
        #pragma unroll
        for (int i = 0; i < 4; ++i) {
            float mx = fmaxf(fmaxf(s[i][0], s[i][1]), fmaxf(s[i][2], s[i][3]));
            #pragma unroll
            for (int off = 8; off; off >>= 1) mx = fmaxf(mx, __shfl_xor(mx, off, 16));
            const float mnew = fmaxf(m_r[i], mx);
            const float alpha = __expf(m_r[i] - mnew);
            float ps = 0.f;
            #pragma unroll
            for (int jj = 0; jj < 4; ++jj) {
                float p = __expf(s[i][jj] - mnew);
                Ps[tx * 4 + jj][ty * 4 + i] = p;
                ps += p;
            }
            #pragma unroll
            for (int off = 8; off; off >>= 1) ps += __shfl_xor(ps, off, 16);
            l_r[i] = l_r[i] * alpha + ps;
            m_r[i] = mnew;
            #pragma unroll
            for (int c = 0; c < 8; ++c) out[i][c] *= alpha;
        }
        __syncthreads();   // Ps visible to all

        // PV: out[4][8] += P[r][j] * V[j][c], cols c = 8tx..+7
        #pragma unroll 4
        for (int j = 0; j < 64; ++j) {
            float4 p  = *(const float4*)&Ps[j][ty * 4];
            float4 v0 = *(const float4*)&Vs[j][tx * 8];
            float4 v1 = *(const float4*)&Vs[j][tx * 8 + 4];
            float pv[4] = {p.x, p.y, p.z, p.w};
            float vv[8] = {v0.x, v0.y, v0.z, v0.w, v1.x, v1.y, v1.z, v1.w};
            #pragma unroll
            for (int i = 0; i < 4; ++i)
                #pragma unroll
                for (int c = 0; c < 8; ++c)
                    out[i][c] = fmaf(pv[i], vv[c], out[i][c]);
        }
    }

    #pragma unroll
    for (int i = 0; i < 4; ++i) {
        const float inv = 1.0f / l_r[i];
        float* op = O + (size_t)(q0 + ty * 4 + i) * DIMN + head * HDIM + tx * 8;
        float4 o0, o1;
        o0.x = out[i][0] * inv; o0.y = out[i][1] * inv;
        o0.z = out[i][2] * inv; o0.w = out[i][3] * inv;
        o1.x = out[i][4] * inv; o1.y = out[i][5] * inv;
        o1.z = out[i][6] * inv; o1.w = out[i][7] * inv;
        *(float4*)(op + 0) = o0;
        *(float4*)(op + 4) = o1;
    }
}

// ---------------------------------------------------------------------------
extern "C" void kernel_launch(void* const* d_in, const int* in_sizes, int n_in,
                              void* d_out, int out_size, void* d_ws, size_t ws_size,
                              hipStream_t stream)
{
    const float* x     = (const float*)d_in[0];
    const float* freqs = (const float*)d_in[1];
    const float* wq    = (const float*)d_in[2];
    const float* bq    = (const float*)d_in[3];
    const float* wk    = (const float*)d_in[4];
    const float* bk    = (const float*)d_in[5];
    const float* wv    = (const float*)d_in[6];
    const float* bv    = (const float*)d_in[7];
    const float* wo    = (const float*)d_in[8];
    const float* bo    = (const float*)d_in[9];
    const float* gq    = (const float*)d_in[10];
    const float* gk    = (const float*)d_in[11];
    const int* seq_lens   = (const int*)d_in[12];
    const int* grid_sizes = (const int*)d_in[13];
    float* out = (float*)d_out;

    const size_t NELEM = (size_t)SLEN * DIMN;
    float* qbuf = (float*)d_ws;
    float* kbuf = qbuf + NELEM;
    float* vbuf = kbuf + NELEM;
    float* obuf = vbuf + NELEM;

    dim3 gblk(DIMN / 64, SLEN / 64);
    gemm_xwt<<<gblk, 256, 0, stream>>>(x, wq, bq, qbuf, SLEN, DIMN, DIMN);
    gemm_xwt<<<gblk, 256, 0, stream>>>(x, wk, bk, kbuf, SLEN, DIMN, DIMN);
    gemm_xwt<<<gblk, 256, 0, stream>>>(x, wv, bv, vbuf, SLEN, DIMN, DIMN);

    rms_rope<<<SLEN, 256, 0, stream>>>(qbuf, gq, freqs, grid_sizes);
    rms_rope<<<SLEN, 256, 0, stream>>>(kbuf, gk, freqs, grid_sizes);

    attention<<<dim3(SLEN / 64, NHEAD), 256, 0, stream>>>(qbuf, kbuf, vbuf, obuf, seq_lens);

    gemm_xwt<<<gblk, 256, 0, stream>>>(obuf, wo, bo, out, SLEN, DIMN, DIMN);
}

// Round 3
// 491.629 us; speedup vs baseline: 15.1285x; 2.5681x over previous
//
#include <hip/hip_runtime.h>
#include <math.h>

#define DIMN 1536
#define NHEAD 12
#define HDIM 128
#define SLEN 2048
#define EPSV 1e-6f

typedef __attribute__((ext_vector_type(8))) short short8;
typedef __attribute__((ext_vector_type(4))) short short4v;
typedef __attribute__((ext_vector_type(4))) float f32x4;

__device__ inline short to_bf16(float f) {
    union { float f; unsigned u; } v; v.f = f;
    unsigned r = (v.u + 0x7FFFu + ((v.u >> 16) & 1u)) >> 16;
    return (short)r;
}
__device__ inline float bf_to_f(short h) {
    union { unsigned u; float f; } v;
    v.u = ((unsigned)(unsigned short)h) << 16;
    return v.f;
}

// ---------------------------------------------------------------------------
// Cast 5 fp32 tensors to bf16 (x + 4 weights), one launch. 8 elems/thread.
// ---------------------------------------------------------------------------
__global__ __launch_bounds__(256)
void cast5(const float* s0, const float* s1, const float* s2,
           const float* s3, const float* s4,
           short* d0, short* d1, short* d2, short* d3, short* d4,
           int n0, int nw)
{
    const float* s; short* d; int n;
    switch (blockIdx.y) {
        case 0: s = s0; d = d0; n = n0; break;
        case 1: s = s1; d = d1; n = nw; break;
        case 2: s = s2; d = d2; n = nw; break;
        case 3: s = s3; d = d3; n = nw; break;
        default: s = s4; d = d4; n = nw; break;
    }
    int idx = (blockIdx.x * 256 + threadIdx.x) * 8;
    if (idx >= n) return;
    float4 a = *(const float4*)(s + idx);
    float4 b = *(const float4*)(s + idx + 4);
    short8 r;
    r[0] = to_bf16(a.x); r[1] = to_bf16(a.y); r[2] = to_bf16(a.z); r[3] = to_bf16(a.w);
    r[4] = to_bf16(b.x); r[5] = to_bf16(b.y); r[6] = to_bf16(b.z); r[7] = to_bf16(b.w);
    *(short8*)(d + idx) = r;
}

// ---------------------------------------------------------------------------
// MFMA GEMM: Y[m,n] = bias[n] + sum_k A[m,k]*W[n,k], A,W bf16, acc fp32.
// 128x128 tile, BK=32, 4 waves (2x2), 4x4 16x16x32 MFMA tiles per wave.
// LDS pitch 40 elems (80 B) -> 2-way-max bank aliasing on b128 frag reads.
// ---------------------------------------------------------------------------
template<bool F32OUT>
__global__ __launch_bounds__(256)
void gemm_bf16(const short* __restrict__ A, const short* __restrict__ W,
               const float* __restrict__ bias, float* __restrict__ Yf,
               short* __restrict__ Yh, int M, int N, int K)
{
    __shared__ short As[128 * 40];
    __shared__ short Bs[128 * 40];

    const int tid = threadIdx.x;
    const int wave = tid >> 6, lane = tid & 63;
    const int quad = lane >> 4, col = lane & 15;
    const int wm = wave >> 1, wn = wave & 1;
    const int m0 = blockIdx.y * 128, n0 = blockIdx.x * 128;
    const int srow = tid >> 2;
    const int schunk = (tid & 3) * 8;

    f32x4 acc[4][4];
    #pragma unroll
    for (int i = 0; i < 4; ++i)
        #pragma unroll
        for (int j = 0; j < 4; ++j)
            #pragma unroll
            for (int r = 0; r < 4; ++r) acc[i][j][r] = 0.f;

    for (int kt = 0; kt < K; kt += 32) {
        short8 a0 = *(const short8*)(A + (size_t)(m0 + srow) * K + kt + schunk);
        short8 a1 = *(const short8*)(A + (size_t)(m0 + srow + 64) * K + kt + schunk);
        short8 b0 = *(const short8*)(W + (size_t)(n0 + srow) * K + kt + schunk);
        short8 b1 = *(const short8*)(W + (size_t)(n0 + srow + 64) * K + kt + schunk);
        __syncthreads();
        *(short8*)&As[srow * 40 + schunk] = a0;
        *(short8*)&As[(srow + 64) * 40 + schunk] = a1;
        *(short8*)&Bs[srow * 40 + schunk] = b0;
        *(short8*)&Bs[(srow + 64) * 40 + schunk] = b1;
        __syncthreads();

        short8 af[4], bf[4];
        #pragma unroll
        for (int mt = 0; mt < 4; ++mt)
            af[mt] = *(const short8*)&As[(wm * 64 + mt * 16 + col) * 40 + quad * 8];
        #pragma unroll
        for (int nt = 0; nt < 4; ++nt)
            bf[nt] = *(const short8*)&Bs[(wn * 64 + nt * 16 + col) * 40 + quad * 8];
        #pragma unroll
        for (int mt = 0; mt < 4; ++mt)
            #pragma unroll
            for (int nt = 0; nt < 4; ++nt)
                acc[mt][nt] = __builtin_amdgcn_mfma_f32_16x16x32_bf16(
                    af[mt], bf[nt], acc[mt][nt], 0, 0, 0);
    }

    #pragma unroll
    for (int mt = 0; mt < 4; ++mt) {
        #pragma unroll
        for (int nt = 0; nt < 4; ++nt) {
            const int n = n0 + wn * 64 + nt * 16 + col;
            const float bb = bias[n];
            #pragma unroll
            for (int r = 0; r < 4; ++r) {
                const int m = m0 + wm * 64 + mt * 16 + quad * 4 + r;
                const float v = acc[mt][nt][r] + bb;
                if (F32OUT) Yf[(size_t)m * N + n] = v;
                else        Yh[(size_t)m * N + n] = to_bf16(v);
            }
        }
    }
}

// ---------------------------------------------------------------------------
// RMSNorm + RoPE on bf16 buffer, in place. extra_scale folds 1/sqrt(HD) for q.
// ---------------------------------------------------------------------------
__global__ __launch_bounds__(256)
void rms_rope_bf16(short* __restrict__ buf, const float* __restrict__ g,
                   const float* __restrict__ freqs, const int* __restrict__ grid_sizes,
                   float extra_scale)
{
    const int s = blockIdx.x;
    const int tid = threadIdx.x;
    short* row = buf + (size_t)s * DIMN;

    float ss = 0.f;
    if (tid < 192) {
        short8 v = *(const short8*)(row + tid * 8);
        #pragma unroll
        for (int j = 0; j < 8; ++j) { float f = bf_to_f(v[j]); ss += f * f; }
    }
    #pragma unroll
    for (int off = 32; off; off >>= 1) ss += __shfl_down(ss, off, 64);

    __shared__ float red[4];
    __shared__ float s_scale;
    if ((tid & 63) == 0) red[tid >> 6] = ss;
    __syncthreads();
    if (tid == 0) {
        float t = red[0] + red[1] + red[2] + red[3];
        s_scale = rsqrtf(t / (float)DIMN + EPSV) * extra_scale;
    }
    __syncthreads();
    const float scale = s_scale;

    const int h = grid_sizes[1], w = grid_sizes[2];
    const int fi = s / (h * w);
    const int hi = (s / w) % h;
    const int wi = s % w;

    for (int p = tid; p < NHEAD * 64; p += 256) {
        const int n = p >> 6;
        const int d = p & 63;
        const int idx = (d < 22) ? fi : ((d < 43) ? hi : wi);
        const float ang = freqs[idx * 64 + d];
        const float cs = cosf(ang), sn = sinf(ang);
        const int base = n * HDIM + 2 * d;
        const float v0 = bf_to_f(row[base]) * scale * g[base];
        const float v1 = bf_to_f(row[base + 1]) * scale * g[base + 1];
        row[base]     = to_bf16(v0 * cs - v1 * sn);
        row[base + 1] = to_bf16(v0 * sn + v1 * cs);
    }
}

// ---------------------------------------------------------------------------
// Transpose bf16 [2048][1536] -> [1536][2048] via 32x32 LDS tiles.
// ---------------------------------------------------------------------------
__global__ __launch_bounds__(256)
void transpose_bf16(const short* __restrict__ in, short* __restrict__ out)
{
    __shared__ short T[32][33];
    const int k0 = blockIdx.y * 32;   // key
    const int d0 = blockIdx.x * 32;   // dim
    const int r = threadIdx.x >> 3;
    const int c4 = (threadIdx.x & 7) * 4;
    short4v v = *(const short4v*)(in + (size_t)(k0 + r) * DIMN + d0 + c4);
    T[r][c4 + 0] = v[0]; T[r][c4 + 1] = v[1];
    T[r][c4 + 2] = v[2]; T[r][c4 + 3] = v[3];
    __syncthreads();
    short4v o;
    o[0] = T[c4 + 0][r]; o[1] = T[c4 + 1][r];
    o[2] = T[c4 + 2][r]; o[3] = T[c4 + 3][r];
    *(short4v*)(out + (size_t)(d0 + r) * SLEN + k0 + c4) = o;
}

// ---------------------------------------------------------------------------
// MFMA flash attention. Block = (128 q-rows, head), 4 waves, each wave owns
// 32 q-rows. K iterated 64 keys/step. K/V fragments direct from global (L2);
// P through per-wave LDS (no barriers). Q frags persistent in registers.
// Q pre-scaled by 1/sqrt(HD); VT is [dim][key].
// ---------------------------------------------------------------------------
__global__ __launch_bounds__(256)
void attn_mfma(const short* __restrict__ Q, const short* __restrict__ K,
               const short* __restrict__ VT, short* __restrict__ O,
               const int* __restrict__ seq_lens)
{
    __shared__ short Ps[4][32 * 88];   // per wave: 32 rows x pitch 88

    const int tid = threadIdx.x;
    const int wave = tid >> 6, lane = tid & 63;
    const int quad = lane >> 4, col = lane & 15;
    const int head = blockIdx.y;
    const int q0 = blockIdx.x * 128 + wave * 32;
    const int slen = seq_lens[0];
    short* psw = &Ps[wave][0];

    // persistent Q A-fragments: [mt][kc]
    short8 qf[2][4];
    #pragma unroll
    for (int mt = 0; mt < 2; ++mt)
        #pragma unroll
        for (int kc = 0; kc < 4; ++kc)
            qf[mt][kc] = *(const short8*)(Q + (size_t)(q0 + mt * 16 + col) * DIMN
                                          + head * HDIM + kc * 32 + quad * 8);

    f32x4 oacc[2][8];
    #pragma unroll
    for (int mt = 0; mt < 2; ++mt)
        #pragma unroll
        for (int dt = 0; dt < 8; ++dt)
            #pragma unroll
            for (int r = 0; r < 4; ++r) oacc[mt][dt][r] = 0.f;

    float mr[2][4], lr[2][4];
    #pragma unroll
    for (int mt = 0; mt < 2; ++mt)
        #pragma unroll
        for (int r = 0; r < 4; ++r) { mr[mt][r] = -1e30f; lr[mt][r] = 0.f; }

    for (int kt = 0; kt < SLEN; kt += 64) {
        // ---- S = Q K^T  (64x64 per wave's 32 rows x 64 keys) ----
        f32x4 s[2][4];
        #pragma unroll
        for (int mt = 0; mt < 2; ++mt)
            #pragma unroll
            for (int nt = 0; nt < 4; ++nt)
                #pragma unroll
                for (int r = 0; r < 4; ++r) s[mt][nt][r] = 0.f;

        #pragma unroll
        for (int kc = 0; kc < 4; ++kc) {
            short8 kf[4];
            #pragma unroll
            for (int nt = 0; nt < 4; ++nt)
                kf[nt] = *(const short8*)(K + (size_t)(kt + nt * 16 + col) * DIMN
                                          + head * HDIM + kc * 32 + quad * 8);
            #pragma unroll
            for (int mt = 0; mt < 2; ++mt)
                #pragma unroll
                for (int nt = 0; nt < 4; ++nt)
                    s[mt][nt] = __builtin_amdgcn_mfma_f32_16x16x32_bf16(
                        qf[mt][kc], kf[nt], s[mt][nt], 0, 0, 0);
        }

        // ---- mask + online softmax (row stats across 16 lanes of quad) ----
        #pragma unroll
        for (int mt = 0; mt < 2; ++mt) {
            #pragma unroll
            for (int nt = 0; nt < 4; ++nt)
                if (kt + nt * 16 + col >= slen)
                    #pragma unroll
                    for (int r = 0; r < 4; ++r) s[mt][nt][r] = -1e30f;

            #pragma unroll
            for (int r = 0; r < 4; ++r) {
                float mx = fmaxf(fmaxf(s[mt][0][r], s[mt][1][r]),
                                 fmaxf(s[mt][2][r], s[mt][3][r]));
                #pragma unroll
                for (int off = 8; off; off >>= 1) mx = fmaxf(mx, __shfl_xor(mx, off, 64));
                const float mnew = fmaxf(mr[mt][r], mx);
                const float alpha = __expf(mr[mt][r] - mnew);
                float ps = 0.f;
                const int prow = (mt * 16 + quad * 4 + r) * 88;
                #pragma unroll
                for (int nt = 0; nt < 4; ++nt) {
                    float p = __expf(s[mt][nt][r] - mnew);
                    ps += p;
                    psw[prow + nt * 16 + col] = to_bf16(p);
                }
                #pragma unroll
                for (int off = 8; off; off >>= 1) ps += __shfl_xor(ps, off, 64);
                lr[mt][r] = lr[mt][r] * alpha + ps;
                mr[mt][r] = mnew;
                #pragma unroll
                for (int dt = 0; dt < 8; ++dt) oacc[mt][dt][r] *= alpha;
            }
        }

        // ---- PV: read P back as A-frags, V^T frags from global ----
        short8 pf[2][2];
        #pragma unroll
        for (int mt = 0; mt < 2; ++mt)
            #pragma unroll
            for (int kc = 0; kc < 2; ++kc)
                pf[mt][kc] = *(const short8*)&psw[(mt * 16 + col) * 88 + kc * 32 + quad * 8];

        #pragma unroll
        for (int dt = 0; dt < 8; ++dt) {
            short8 vf[2];
            #pragma unroll
            for (int kc = 0; kc < 2; ++kc)
                vf[kc] = *(const short8*)(VT + (size_t)(head * HDIM + dt * 16 + col) * SLEN
                                          + kt + kc * 32 + quad * 8);
            #pragma unroll
            for (int mt = 0; mt < 2; ++mt)
                #pragma unroll
                for (int kc = 0; kc < 2; ++kc)
                    oacc[mt][dt] = __builtin_amdgcn_mfma_f32_16x16x32_bf16(
                        pf[mt][kc], vf[kc], oacc[mt][dt], 0, 0, 0);
        }
    }

    // ---- epilogue: divide by l, store bf16 ----
    #pragma unroll
    for (int mt = 0; mt < 2; ++mt) {
        float inv[4];
        #pragma unroll
        for (int r = 0; r < 4; ++r) inv[r] = 1.0f / lr[mt][r];
        #pragma unroll
        for (int dt = 0; dt < 8; ++dt) {
            const int d = head * HDIM + dt * 16 + col;
            #pragma unroll
            for (int r = 0; r < 4; ++r) {
                const int row = q0 + mt * 16 + quad * 4 + r;
                O[(size_t)row * DIMN + d] = to_bf16(oacc[mt][dt][r] * inv[r]);
            }
        }
    }
}

// ---------------------------------------------------------------------------
extern "C" void kernel_launch(void* const* d_in, const int* in_sizes, int n_in,
                              void* d_out, int out_size, void* d_ws, size_t ws_size,
                              hipStream_t stream)
{
    const float* x     = (const float*)d_in[0];
    const float* freqs = (const float*)d_in[1];
    const float* wq    = (const float*)d_in[2];
    const float* bq    = (const float*)d_in[3];
    const float* wk    = (const float*)d_in[4];
    const float* bk    = (const float*)d_in[5];
    const float* wv    = (const float*)d_in[6];
    const float* bv    = (const float*)d_in[7];
    const float* wo    = (const float*)d_in[8];
    const float* bo    = (const float*)d_in[9];
    const float* gq    = (const float*)d_in[10];
    const float* gk    = (const float*)d_in[11];
    const int* seq_lens   = (const int*)d_in[12];
    const int* grid_sizes = (const int*)d_in[13];
    float* out = (float*)d_out;

    const size_t NX = (size_t)SLEN * DIMN;       // 3,145,728
    const size_t NW = (size_t)DIMN * DIMN;       // 2,359,296
    short* xb  = (short*)d_ws;
    short* wqb = xb + NX;
    short* wkb = wqb + NW;
    short* wvb = wkb + NW;
    short* wob = wvb + NW;
    short* qb  = wob + NW;
    short* kb  = qb + NX;
    short* vb  = kb + NX;      // reused as attention output after transpose
    short* vt  = vb + NX;
    short* ob  = vb;

    // 1) casts (one launch, 5 tensors)
    cast5<<<dim3(1536, 5), 256, 0, stream>>>(x, wq, wk, wv, wo,
                                             xb, wqb, wkb, wvb, wob,
                                             (int)NX, (int)NW);

    // 2) QKV projections
    dim3 gg(DIMN / 128, SLEN / 128);
    gemm_bf16<false><<<gg, 256, 0, stream>>>(xb, wqb, bq, nullptr, qb, SLEN, DIMN, DIMN);
    gemm_bf16<false><<<gg, 256, 0, stream>>>(xb, wkb, bk, nullptr, kb, SLEN, DIMN, DIMN);
    gemm_bf16<false><<<gg, 256, 0, stream>>>(xb, wvb, bv, nullptr, vb, SLEN, DIMN, DIMN);

    // 3) rmsnorm + rope (q gets 1/sqrt(HD) folded in)
    rms_rope_bf16<<<SLEN, 256, 0, stream>>>(qb, gq, freqs, grid_sizes, 0.08838834764831845f);
    rms_rope_bf16<<<SLEN, 256, 0, stream>>>(kb, gk, freqs, grid_sizes, 1.0f);

    // 4) V -> V^T  [1536][2048]
    transpose_bf16<<<dim3(DIMN / 32, SLEN / 32), 256, 0, stream>>>(vb, vt);

    // 5) attention (writes ob == vb, safe: vb dead after transpose)
    attn_mfma<<<dim3(SLEN / 128, NHEAD), 256, 0, stream>>>(qb, kb, vt, ob, seq_lens);

    // 6) output projection -> fp32 d_out
    gemm_bf16<true><<<gg, 256, 0, stream>>>(ob, wob, bo, out, nullptr, SLEN, DIMN, DIMN);
}

// Round 4
// 491.114 us; speedup vs baseline: 15.1444x; 1.0010x over previous
//
#include <hip/hip_runtime.h>
#include <math.h>

#define DIMN 1536
#define NHEAD 12
#define HDIM 128
#define SLEN 2048
#define EPSV 1e-6f

typedef __attribute__((ext_vector_type(8))) short short8;
typedef __attribute__((ext_vector_type(4))) short short4v;
typedef __attribute__((ext_vector_type(4))) float f32x4;

__device__ inline short to_bf16(float f) {
    union { float f; unsigned u; } v; v.f = f;
    unsigned r = (v.u + 0x7FFFu + ((v.u >> 16) & 1u)) >> 16;
    return (short)r;
}
__device__ inline float bf_to_f(short h) {
    union { unsigned u; float f; } v;
    v.u = ((unsigned)(unsigned short)h) << 16;
    return v.f;
}

// ---------------------------------------------------------------------------
// Cast 5 fp32 tensors to bf16 (x + 4 weights), one launch. 8 elems/thread.
// ---------------------------------------------------------------------------
__global__ __launch_bounds__(256)
void cast5(const float* s0, const float* s1, const float* s2,
           const float* s3, const float* s4,
           short* d0, short* d1, short* d2, short* d3, short* d4,
           int n0, int nw)
{
    const float* s; short* d; int n;
    switch (blockIdx.y) {
        case 0: s = s0; d = d0; n = n0; break;
        case 1: s = s1; d = d1; n = nw; break;
        case 2: s = s2; d = d2; n = nw; break;
        case 3: s = s3; d = d3; n = nw; break;
        default: s = s4; d = d4; n = nw; break;
    }
    int idx = (blockIdx.x * 256 + threadIdx.x) * 8;
    if (idx >= n) return;
    float4 a = *(const float4*)(s + idx);
    float4 b = *(const float4*)(s + idx + 4);
    short8 r;
    r[0] = to_bf16(a.x); r[1] = to_bf16(a.y); r[2] = to_bf16(a.z); r[3] = to_bf16(a.w);
    r[4] = to_bf16(b.x); r[5] = to_bf16(b.y); r[6] = to_bf16(b.z); r[7] = to_bf16(b.w);
    *(short8*)(d + idx) = r;
}

// ---------------------------------------------------------------------------
// Fused QKV MFMA GEMM: for sel in {q,k,v}: Y[m,n] = b[n] + sum_k A[m,k]W[n,k].
// 128x128 tile, BK=32, 4 waves (2x2), 4x4 16x16x32 MFMA tiles per wave.
// grid.x = 3*12 = 36 tiles in n (sel = x/12), grid.y = 16 tiles in m.
// ---------------------------------------------------------------------------
__global__ __launch_bounds__(256)
void gemm_qkv(const short* __restrict__ A,
              const short* __restrict__ W0, const short* __restrict__ W1,
              const short* __restrict__ W2,
              const float* __restrict__ b0, const float* __restrict__ b1,
              const float* __restrict__ b2,
              short* __restrict__ Y0, short* __restrict__ Y1,
              short* __restrict__ Y2)
{
    __shared__ short As[128 * 40];
    __shared__ short Bs[128 * 40];

    const int sel = blockIdx.x / (DIMN / 128);
    const int nb  = blockIdx.x % (DIMN / 128);
    const short* W   = (sel == 0) ? W0 : (sel == 1) ? W1 : W2;
    const float* bias= (sel == 0) ? b0 : (sel == 1) ? b1 : b2;
    short* Y         = (sel == 0) ? Y0 : (sel == 1) ? Y1 : Y2;

    const int tid = threadIdx.x;
    const int wave = tid >> 6, lane = tid & 63;
    const int quad = lane >> 4, col = lane & 15;
    const int wm = wave >> 1, wn = wave & 1;
    const int m0 = blockIdx.y * 128, n0 = nb * 128;
    const int srow = tid >> 2;
    const int schunk = (tid & 3) * 8;

    f32x4 acc[4][4];
    #pragma unroll
    for (int i = 0; i < 4; ++i)
        #pragma unroll
        for (int j = 0; j < 4; ++j)
            #pragma unroll
            for (int r = 0; r < 4; ++r) acc[i][j][r] = 0.f;

    for (int kt = 0; kt < DIMN; kt += 32) {
        short8 a0 = *(const short8*)(A + (size_t)(m0 + srow) * DIMN + kt + schunk);
        short8 a1 = *(const short8*)(A + (size_t)(m0 + srow + 64) * DIMN + kt + schunk);
        short8 bb0 = *(const short8*)(W + (size_t)(n0 + srow) * DIMN + kt + schunk);
        short8 bb1 = *(const short8*)(W + (size_t)(n0 + srow + 64) * DIMN + kt + schunk);
        __syncthreads();
        *(short8*)&As[srow * 40 + schunk] = a0;
        *(short8*)&As[(srow + 64) * 40 + schunk] = a1;
        *(short8*)&Bs[srow * 40 + schunk] = bb0;
        *(short8*)&Bs[(srow + 64) * 40 + schunk] = bb1;
        __syncthreads();

        short8 af[4], bf[4];
        #pragma unroll
        for (int mt = 0; mt < 4; ++mt)
            af[mt] = *(const short8*)&As[(wm * 64 + mt * 16 + col) * 40 + quad * 8];
        #pragma unroll
        for (int nt = 0; nt < 4; ++nt)
            bf[nt] = *(const short8*)&Bs[(wn * 64 + nt * 16 + col) * 40 + quad * 8];
        #pragma unroll
        for (int mt = 0; mt < 4; ++mt)
            #pragma unroll
            for (int nt = 0; nt < 4; ++nt)
                acc[mt][nt] = __builtin_amdgcn_mfma_f32_16x16x32_bf16(
                    af[mt], bf[nt], acc[mt][nt], 0, 0, 0);
    }

    #pragma unroll
    for (int mt = 0; mt < 4; ++mt) {
        #pragma unroll
        for (int nt = 0; nt < 4; ++nt) {
            const int n = n0 + wn * 64 + nt * 16 + col;
            const float bb = bias[n];
            #pragma unroll
            for (int r = 0; r < 4; ++r) {
                const int m = m0 + wm * 64 + mt * 16 + quad * 4 + r;
                Y[(size_t)m * DIMN + n] = to_bf16(acc[mt][nt][r] + bb);
            }
        }
    }
}

// ---------------------------------------------------------------------------
// Output-projection GEMM, fp32 out.
// ---------------------------------------------------------------------------
__global__ __launch_bounds__(256)
void gemm_out(const short* __restrict__ A, const short* __restrict__ W,
              const float* __restrict__ bias, float* __restrict__ Yf)
{
    __shared__ short As[128 * 40];
    __shared__ short Bs[128 * 40];

    const int tid = threadIdx.x;
    const int wave = tid >> 6, lane = tid & 63;
    const int quad = lane >> 4, col = lane & 15;
    const int wm = wave >> 1, wn = wave & 1;
    const int m0 = blockIdx.y * 128, n0 = blockIdx.x * 128;
    const int srow = tid >> 2;
    const int schunk = (tid & 3) * 8;

    f32x4 acc[4][4];
    #pragma unroll
    for (int i = 0; i < 4; ++i)
        #pragma unroll
        for (int j = 0; j < 4; ++j)
            #pragma unroll
            for (int r = 0; r < 4; ++r) acc[i][j][r] = 0.f;

    for (int kt = 0; kt < DIMN; kt += 32) {
        short8 a0 = *(const short8*)(A + (size_t)(m0 + srow) * DIMN + kt + schunk);
        short8 a1 = *(const short8*)(A + (size_t)(m0 + srow + 64) * DIMN + kt + schunk);
        short8 bb0 = *(const short8*)(W + (size_t)(n0 + srow) * DIMN + kt + schunk);
        short8 bb1 = *(const short8*)(W + (size_t)(n0 + srow + 64) * DIMN + kt + schunk);
        __syncthreads();
        *(short8*)&As[srow * 40 + schunk] = a0;
        *(short8*)&As[(srow + 64) * 40 + schunk] = a1;
        *(short8*)&Bs[srow * 40 + schunk] = bb0;
        *(short8*)&Bs[(srow + 64) * 40 + schunk] = bb1;
        __syncthreads();

        short8 af[4], bf[4];
        #pragma unroll
        for (int mt = 0; mt < 4; ++mt)
            af[mt] = *(const short8*)&As[(wm * 64 + mt * 16 + col) * 40 + quad * 8];
        #pragma unroll
        for (int nt = 0; nt < 4; ++nt)
            bf[nt] = *(const short8*)&Bs[(wn * 64 + nt * 16 + col) * 40 + quad * 8];
        #pragma unroll
        for (int mt = 0; mt < 4; ++mt)
            #pragma unroll
            for (int nt = 0; nt < 4; ++nt)
                acc[mt][nt] = __builtin_amdgcn_mfma_f32_16x16x32_bf16(
                    af[mt], bf[nt], acc[mt][nt], 0, 0, 0);
    }

    #pragma unroll
    for (int mt = 0; mt < 4; ++mt) {
        #pragma unroll
        for (int nt = 0; nt < 4; ++nt) {
            const int n = n0 + wn * 64 + nt * 16 + col;
            const float bb = bias[n];
            #pragma unroll
            for (int r = 0; r < 4; ++r) {
                const int m = m0 + wm * 64 + mt * 16 + quad * 4 + r;
                Yf[(size_t)m * DIMN + n] = acc[mt][nt][r] + bb;
            }
        }
    }
}

// ---------------------------------------------------------------------------
// RMSNorm + RoPE on bf16 buffer, in place. extra_scale folds 1/sqrt(HD) for q.
// ---------------------------------------------------------------------------
__global__ __launch_bounds__(256)
void rms_rope_bf16(short* __restrict__ buf, const float* __restrict__ g,
                   const float* __restrict__ freqs, const int* __restrict__ grid_sizes,
                   float extra_scale)
{
    const int s = blockIdx.x;
    const int tid = threadIdx.x;
    short* row = buf + (size_t)s * DIMN;

    float ss = 0.f;
    if (tid < 192) {
        short8 v = *(const short8*)(row + tid * 8);
        #pragma unroll
        for (int j = 0; j < 8; ++j) { float f = bf_to_f(v[j]); ss += f * f; }
    }
    #pragma unroll
    for (int off = 32; off; off >>= 1) ss += __shfl_down(ss, off, 64);

    __shared__ float red[4];
    __shared__ float s_scale;
    if ((tid & 63) == 0) red[tid >> 6] = ss;
    __syncthreads();
    if (tid == 0) {
        float t = red[0] + red[1] + red[2] + red[3];
        s_scale = rsqrtf(t / (float)DIMN + EPSV) * extra_scale;
    }
    __syncthreads();
    const float scale = s_scale;

    const int h = grid_sizes[1], w = grid_sizes[2];
    const int fi = s / (h * w);
    const int hi = (s / w) % h;
    const int wi = s % w;

    for (int p = tid; p < NHEAD * 64; p += 256) {
        const int n = p >> 6;
        const int d = p & 63;
        const int idx = (d < 22) ? fi : ((d < 43) ? hi : wi);
        const float ang = freqs[idx * 64 + d];
        const float cs = cosf(ang), sn = sinf(ang);
        const int base = n * HDIM + 2 * d;
        const float v0 = bf_to_f(row[base]) * scale * g[base];
        const float v1 = bf_to_f(row[base + 1]) * scale * g[base + 1];
        row[base]     = to_bf16(v0 * cs - v1 * sn);
        row[base + 1] = to_bf16(v0 * sn + v1 * cs);
    }
}

// ---------------------------------------------------------------------------
// Transpose bf16 [2048][1536] -> [1536][2048] via 32x32 LDS tiles.
// ---------------------------------------------------------------------------
__global__ __launch_bounds__(256)
void transpose_bf16(const short* __restrict__ in, short* __restrict__ out)
{
    __shared__ short T[32][33];
    const int k0 = blockIdx.y * 32;
    const int d0 = blockIdx.x * 32;
    const int r = threadIdx.x >> 3;
    const int c4 = (threadIdx.x & 7) * 4;
    short4v v = *(const short4v*)(in + (size_t)(k0 + r) * DIMN + d0 + c4);
    T[r][c4 + 0] = v[0]; T[r][c4 + 1] = v[1];
    T[r][c4 + 2] = v[2]; T[r][c4 + 3] = v[3];
    __syncthreads();
    short4v o;
    o[0] = T[c4 + 0][r]; o[1] = T[c4 + 1][r];
    o[2] = T[c4 + 2][r]; o[3] = T[c4 + 3][r];
    *(short4v*)(out + (size_t)(d0 + r) * SLEN + k0 + c4) = o;
}

// ---------------------------------------------------------------------------
// MFMA flash attention v2 — max-free softmax (|s| <= sqrt(HD) bound after
// RMSNorm makes exp(s) overflow-safe), so no online max, no alpha rescale,
// no in-loop shuffles, and K-split partials just add.
// Block = 512 threads (8 waves), 64 q-rows, head = blockIdx.y.
// Waves 0-3: rows w*16, keys [0,1024). Waves 4-7: same rows, keys [1024,2048).
// Single barrier: LDS combine of the two key-half partials.
// ---------------------------------------------------------------------------
__global__ __launch_bounds__(512)
void attn_mfma2(const short* __restrict__ Q, const short* __restrict__ K,
                const short* __restrict__ VT, short* __restrict__ O,
                const int* __restrict__ seq_lens)
{
    __shared__ short Ps[8][16 * 72];        // per-wave P tile, 18 KB
    __shared__ float Oc[4][16][132];        // combine buffer, 33.8 KB
    __shared__ float Lc[4][16];

    const int tid = threadIdx.x;
    const int wave = tid >> 6, lane = tid & 63;
    const int quad = lane >> 4, col = lane & 15;
    const int half = wave >> 2, w4 = wave & 3;
    const int head = blockIdx.y;
    const int row0 = blockIdx.x * 64 + w4 * 16;
    const int slen = seq_lens[0];
    short* psw = &Ps[wave][0];

    // persistent Q A-fragments (16 rows), Q pre-scaled by 1/sqrt(HD)
    short8 qf[4];
    #pragma unroll
    for (int kc = 0; kc < 4; ++kc)
        qf[kc] = *(const short8*)(Q + (size_t)(row0 + col) * DIMN
                                  + head * HDIM + kc * 32 + quad * 8);

    f32x4 oacc[8];
    #pragma unroll
    for (int dt = 0; dt < 8; ++dt)
        #pragma unroll
        for (int r = 0; r < 4; ++r) oacc[dt][r] = 0.f;
    float lsum[4] = {0.f, 0.f, 0.f, 0.f};

    const int kbeg = half * (SLEN / 2);
    for (int kt = kbeg; kt < kbeg + SLEN / 2; kt += 64) {
        // ---- S = Q K^T (16 rows x 64 keys) ----
        f32x4 s[4];
        #pragma unroll
        for (int nt = 0; nt < 4; ++nt)
            #pragma unroll
            for (int r = 0; r < 4; ++r) s[nt][r] = 0.f;

        #pragma unroll
        for (int kc = 0; kc < 4; ++kc) {
            short8 kf[4];
            #pragma unroll
            for (int nt = 0; nt < 4; ++nt)
                kf[nt] = *(const short8*)(K + (size_t)(kt + nt * 16 + col) * DIMN
                                          + head * HDIM + kc * 32 + quad * 8);
            #pragma unroll
            for (int nt = 0; nt < 4; ++nt)
                s[nt] = __builtin_amdgcn_mfma_f32_16x16x32_bf16(qf[kc], kf[nt], s[nt], 0, 0, 0);
        }

        // ---- mask + exp (no max) + per-lane l accumulation + P store ----
        #pragma unroll
        for (int nt = 0; nt < 4; ++nt) {
            const bool masked = (kt + nt * 16 + col >= slen);
            #pragma unroll
            for (int r = 0; r < 4; ++r) {
                float p = masked ? 0.f : __expf(s[nt][r]);
                lsum[r] += p;
                psw[(quad * 4 + r) * 72 + nt * 16 + col] = to_bf16(p);
            }
        }

        // ---- PV: P back as A-frags, V^T B-frags from global ----
        short8 pf[2];
        #pragma unroll
        for (int kc = 0; kc < 2; ++kc)
            pf[kc] = *(const short8*)&psw[col * 72 + kc * 32 + quad * 8];

        #pragma unroll
        for (int dt = 0; dt < 8; ++dt) {
            short8 vf[2];
            #pragma unroll
            for (int kc = 0; kc < 2; ++kc)
                vf[kc] = *(const short8*)(VT + (size_t)(head * HDIM + dt * 16 + col) * SLEN
                                          + kt + kc * 32 + quad * 8);
            #pragma unroll
            for (int kc = 0; kc < 2; ++kc)
                oacc[dt] = __builtin_amdgcn_mfma_f32_16x16x32_bf16(pf[kc], vf[kc], oacc[dt], 0, 0, 0);
        }
    }

    // ---- one-shot row-sum reduction across the 16 col lanes ----
    #pragma unroll
    for (int r = 0; r < 4; ++r) {
        #pragma unroll
        for (int off = 8; off; off >>= 1) lsum[r] += __shfl_xor(lsum[r], off, 64);
    }

    // ---- combine halves via LDS ----
    if (half == 1) {
        #pragma unroll
        for (int dt = 0; dt < 8; ++dt)
            #pragma unroll
            for (int r = 0; r < 4; ++r)
                Oc[w4][quad * 4 + r][dt * 16 + col] = oacc[dt][r];
        if (col == 0) {
            #pragma unroll
            for (int r = 0; r < 4; ++r) Lc[w4][quad * 4 + r] = lsum[r];
        }
    }
    __syncthreads();
    if (half == 0) {
        float inv[4];
        #pragma unroll
        for (int r = 0; r < 4; ++r)
            inv[r] = 1.0f / (lsum[r] + Lc[w4][quad * 4 + r]);
        #pragma unroll
        for (int dt = 0; dt < 8; ++dt) {
            #pragma unroll
            for (int r = 0; r < 4; ++r) {
                const float v = (oacc[dt][r] + Oc[w4][quad * 4 + r][dt * 16 + col]) * inv[r];
                O[(size_t)(row0 + quad * 4 + r) * DIMN + head * HDIM + dt * 16 + col] = to_bf16(v);
            }
        }
    }
}

// ---------------------------------------------------------------------------
extern "C" void kernel_launch(void* const* d_in, const int* in_sizes, int n_in,
                              void* d_out, int out_size, void* d_ws, size_t ws_size,
                              hipStream_t stream)
{
    const float* x     = (const float*)d_in[0];
    const float* freqs = (const float*)d_in[1];
    const float* wq    = (const float*)d_in[2];
    const float* bq    = (const float*)d_in[3];
    const float* wk    = (const float*)d_in[4];
    const float* bk    = (const float*)d_in[5];
    const float* wv    = (const float*)d_in[6];
    const float* bv    = (const float*)d_in[7];
    const float* wo    = (const float*)d_in[8];
    const float* bo    = (const float*)d_in[9];
    const float* gq    = (const float*)d_in[10];
    const float* gk    = (const float*)d_in[11];
    const int* seq_lens   = (const int*)d_in[12];
    const int* grid_sizes = (const int*)d_in[13];
    float* out = (float*)d_out;

    const size_t NX = (size_t)SLEN * DIMN;
    const size_t NW = (size_t)DIMN * DIMN;
    short* xb  = (short*)d_ws;
    short* wqb = xb + NX;
    short* wkb = wqb + NW;
    short* wvb = wkb + NW;
    short* wob = wvb + NW;
    short* qb  = wob + NW;
    short* kb  = qb + NX;
    short* vb  = kb + NX;
    short* vt  = vb + NX;
    short* ob  = vb;          // vb dead after transpose

    cast5<<<dim3(1536, 5), 256, 0, stream>>>(x, wq, wk, wv, wo,
                                             xb, wqb, wkb, wvb, wob,
                                             (int)NX, (int)NW);

    // fused QKV projections: 36 x 16 = 576 blocks
    gemm_qkv<<<dim3(3 * DIMN / 128, SLEN / 128), 256, 0, stream>>>(
        xb, wqb, wkb, wvb, bq, bk, bv, qb, kb, vb);

    rms_rope_bf16<<<SLEN, 256, 0, stream>>>(qb, gq, freqs, grid_sizes, 0.08838834764831845f);
    rms_rope_bf16<<<SLEN, 256, 0, stream>>>(kb, gk, freqs, grid_sizes, 1.0f);

    transpose_bf16<<<dim3(DIMN / 32, SLEN / 32), 256, 0, stream>>>(vb, vt);

    attn_mfma2<<<dim3(SLEN / 64, NHEAD), 512, 0, stream>>>(qb, kb, vt, ob, seq_lens);

    gemm_out<<<dim3(DIMN / 128, SLEN / 128), 256, 0, stream>>>(ob, wob, bo, out);
}

// Round 5
// 410.088 us; speedup vs baseline: 18.1366x; 1.1976x over previous
//
#include <hip/hip_runtime.h>
#include <math.h>

#define DIMN 1536
#define NHEAD 12
#define HDIM 128
#define SLEN 2048
#define EPSV 1e-6f

typedef __attribute__((ext_vector_type(8))) short short8;
typedef __attribute__((ext_vector_type(4))) short short4v;
typedef __attribute__((ext_vector_type(4))) float f32x4;

__device__ inline short to_bf16(float f) {
    union { float f; unsigned u; } v; v.f = f;
    unsigned r = (v.u + 0x7FFFu + ((v.u >> 16) & 1u)) >> 16;
    return (short)r;
}
__device__ inline float bf_to_f(short h) {
    union { unsigned u; float f; } v;
    v.u = ((unsigned)(unsigned short)h) << 16;
    return v.f;
}

// ---------------------------------------------------------------------------
// Cast 5 fp32 tensors to bf16 (x + 4 weights), one launch. 8 elems/thread.
// ---------------------------------------------------------------------------
__global__ __launch_bounds__(256)
void cast5(const float* s0, const float* s1, const float* s2,
           const float* s3, const float* s4,
           short* d0, short* d1, short* d2, short* d3, short* d4,
           int n0, int nw)
{
    const float* s; short* d; int n;
    switch (blockIdx.y) {
        case 0: s = s0; d = d0; n = n0; break;
        case 1: s = s1; d = d1; n = nw; break;
        case 2: s = s2; d = d2; n = nw; break;
        case 3: s = s3; d = d3; n = nw; break;
        default: s = s4; d = d4; n = nw; break;
    }
    int idx = (blockIdx.x * 256 + threadIdx.x) * 8;
    if (idx >= n) return;
    float4 a = *(const float4*)(s + idx);
    float4 b = *(const float4*)(s + idx + 4);
    short8 r;
    r[0] = to_bf16(a.x); r[1] = to_bf16(a.y); r[2] = to_bf16(a.z); r[3] = to_bf16(a.w);
    r[4] = to_bf16(b.x); r[5] = to_bf16(b.y); r[6] = to_bf16(b.z); r[7] = to_bf16(b.w);
    *(short8*)(d + idx) = r;
}

// ---------------------------------------------------------------------------
// Fused QKV MFMA GEMM: for sel in {q,k,v}: Y[m,n] = b[n] + sum_k A[m,k]W[n,k].
// 128x128 tile, BK=32, 4 waves (2x2), 4x4 16x16x32 MFMA tiles per wave.
// ---------------------------------------------------------------------------
__global__ __launch_bounds__(256)
void gemm_qkv(const short* __restrict__ A,
              const short* __restrict__ W0, const short* __restrict__ W1,
              const short* __restrict__ W2,
              const float* __restrict__ b0, const float* __restrict__ b1,
              const float* __restrict__ b2,
              short* __restrict__ Y0, short* __restrict__ Y1,
              short* __restrict__ Y2)
{
    __shared__ short As[128 * 40];
    __shared__ short Bs[128 * 40];

    const int sel = blockIdx.x / (DIMN / 128);
    const int nb  = blockIdx.x % (DIMN / 128);
    const short* W   = (sel == 0) ? W0 : (sel == 1) ? W1 : W2;
    const float* bias= (sel == 0) ? b0 : (sel == 1) ? b1 : b2;
    short* Y         = (sel == 0) ? Y0 : (sel == 1) ? Y1 : Y2;

    const int tid = threadIdx.x;
    const int wave = tid >> 6, lane = tid & 63;
    const int quad = lane >> 4, col = lane & 15;
    const int wm = wave >> 1, wn = wave & 1;
    const int m0 = blockIdx.y * 128, n0 = nb * 128;
    const int srow = tid >> 2;
    const int schunk = (tid & 3) * 8;

    f32x4 acc[4][4];
    #pragma unroll
    for (int i = 0; i < 4; ++i)
        #pragma unroll
        for (int j = 0; j < 4; ++j)
            #pragma unroll
            for (int r = 0; r < 4; ++r) acc[i][j][r] = 0.f;

    for (int kt = 0; kt < DIMN; kt += 32) {
        short8 a0 = *(const short8*)(A + (size_t)(m0 + srow) * DIMN + kt + schunk);
        short8 a1 = *(const short8*)(A + (size_t)(m0 + srow + 64) * DIMN + kt + schunk);
        short8 bb0 = *(const short8*)(W + (size_t)(n0 + srow) * DIMN + kt + schunk);
        short8 bb1 = *(const short8*)(W + (size_t)(n0 + srow + 64) * DIMN + kt + schunk);
        __syncthreads();
        *(short8*)&As[srow * 40 + schunk] = a0;
        *(short8*)&As[(srow + 64) * 40 + schunk] = a1;
        *(short8*)&Bs[srow * 40 + schunk] = bb0;
        *(short8*)&Bs[(srow + 64) * 40 + schunk] = bb1;
        __syncthreads();

        short8 af[4], bf[4];
        #pragma unroll
        for (int mt = 0; mt < 4; ++mt)
            af[mt] = *(const short8*)&As[(wm * 64 + mt * 16 + col) * 40 + quad * 8];
        #pragma unroll
        for (int nt = 0; nt < 4; ++nt)
            bf[nt] = *(const short8*)&Bs[(wn * 64 + nt * 16 + col) * 40 + quad * 8];
        #pragma unroll
        for (int mt = 0; mt < 4; ++mt)
            #pragma unroll
            for (int nt = 0; nt < 4; ++nt)
                acc[mt][nt] = __builtin_amdgcn_mfma_f32_16x16x32_bf16(
                    af[mt], bf[nt], acc[mt][nt], 0, 0, 0);
    }

    #pragma unroll
    for (int mt = 0; mt < 4; ++mt) {
        #pragma unroll
        for (int nt = 0; nt < 4; ++nt) {
            const int n = n0 + wn * 64 + nt * 16 + col;
            const float bb = bias[n];
            #pragma unroll
            for (int r = 0; r < 4; ++r) {
                const int m = m0 + wm * 64 + mt * 16 + quad * 4 + r;
                Y[(size_t)m * DIMN + n] = to_bf16(acc[mt][nt][r] + bb);
            }
        }
    }
}

// ---------------------------------------------------------------------------
// Output-projection GEMM, fp32 out.
// ---------------------------------------------------------------------------
__global__ __launch_bounds__(256)
void gemm_out(const short* __restrict__ A, const short* __restrict__ W,
              const float* __restrict__ bias, float* __restrict__ Yf)
{
    __shared__ short As[128 * 40];
    __shared__ short Bs[128 * 40];

    const int tid = threadIdx.x;
    const int wave = tid >> 6, lane = tid & 63;
    const int quad = lane >> 4, col = lane & 15;
    const int wm = wave >> 1, wn = wave & 1;
    const int m0 = blockIdx.y * 128, n0 = blockIdx.x * 128;
    const int srow = tid >> 2;
    const int schunk = (tid & 3) * 8;

    f32x4 acc[4][4];
    #pragma unroll
    for (int i = 0; i < 4; ++i)
        #pragma unroll
        for (int j = 0; j < 4; ++j)
            #pragma unroll
            for (int r = 0; r < 4; ++r) acc[i][j][r] = 0.f;

    for (int kt = 0; kt < DIMN; kt += 32) {
        short8 a0 = *(const short8*)(A + (size_t)(m0 + srow) * DIMN + kt + schunk);
        short8 a1 = *(const short8*)(A + (size_t)(m0 + srow + 64) * DIMN + kt + schunk);
        short8 bb0 = *(const short8*)(W + (size_t)(n0 + srow) * DIMN + kt + schunk);
        short8 bb1 = *(const short8*)(W + (size_t)(n0 + srow + 64) * DIMN + kt + schunk);
        __syncthreads();
        *(short8*)&As[srow * 40 + schunk] = a0;
        *(short8*)&As[(srow + 64) * 40 + schunk] = a1;
        *(short8*)&Bs[srow * 40 + schunk] = bb0;
        *(short8*)&Bs[(srow + 64) * 40 + schunk] = bb1;
        __syncthreads();

        short8 af[4], bf[4];
        #pragma unroll
        for (int mt = 0; mt < 4; ++mt)
            af[mt] = *(const short8*)&As[(wm * 64 + mt * 16 + col) * 40 + quad * 8];
        #pragma unroll
        for (int nt = 0; nt < 4; ++nt)
            bf[nt] = *(const short8*)&Bs[(wn * 64 + nt * 16 + col) * 40 + quad * 8];
        #pragma unroll
        for (int mt = 0; mt < 4; ++mt)
            #pragma unroll
            for (int nt = 0; nt < 4; ++nt)
                acc[mt][nt] = __builtin_amdgcn_mfma_f32_16x16x32_bf16(
                    af[mt], bf[nt], acc[mt][nt], 0, 0, 0);
    }

    #pragma unroll
    for (int mt = 0; mt < 4; ++mt) {
        #pragma unroll
        for (int nt = 0; nt < 4; ++nt) {
            const int n = n0 + wn * 64 + nt * 16 + col;
            const float bb = bias[n];
            #pragma unroll
            for (int r = 0; r < 4; ++r) {
                const int m = m0 + wm * 64 + mt * 16 + quad * 4 + r;
                Yf[(size_t)m * DIMN + n] = acc[mt][nt][r] + bb;
            }
        }
    }
}

// ---------------------------------------------------------------------------
// RMSNorm + RoPE on bf16 buffer, in place. extra_scale folds 1/sqrt(HD) for q.
// ---------------------------------------------------------------------------
__global__ __launch_bounds__(256)
void rms_rope_bf16(short* __restrict__ buf, const float* __restrict__ g,
                   const float* __restrict__ freqs, const int* __restrict__ grid_sizes,
                   float extra_scale)
{
    const int s = blockIdx.x;
    const int tid = threadIdx.x;
    short* row = buf + (size_t)s * DIMN;

    float ss = 0.f;
    if (tid < 192) {
        short8 v = *(const short8*)(row + tid * 8);
        #pragma unroll
        for (int j = 0; j < 8; ++j) { float f = bf_to_f(v[j]); ss += f * f; }
    }
    #pragma unroll
    for (int off = 32; off; off >>= 1) ss += __shfl_down(ss, off, 64);

    __shared__ float red[4];
    __shared__ float s_scale;
    if ((tid & 63) == 0) red[tid >> 6] = ss;
    __syncthreads();
    if (tid == 0) {
        float t = red[0] + red[1] + red[2] + red[3];
        s_scale = rsqrtf(t / (float)DIMN + EPSV) * extra_scale;
    }
    __syncthreads();
    const float scale = s_scale;

    const int h = grid_sizes[1], w = grid_sizes[2];
    const int fi = s / (h * w);
    const int hi = (s / w) % h;
    const int wi = s % w;

    for (int p = tid; p < NHEAD * 64; p += 256) {
        const int n = p >> 6;
        const int d = p & 63;
        const int idx = (d < 22) ? fi : ((d < 43) ? hi : wi);
        const float ang = freqs[idx * 64 + d];
        const float cs = cosf(ang), sn = sinf(ang);
        const int base = n * HDIM + 2 * d;
        const float v0 = bf_to_f(row[base]) * scale * g[base];
        const float v1 = bf_to_f(row[base + 1]) * scale * g[base + 1];
        row[base]     = to_bf16(v0 * cs - v1 * sn);
        row[base + 1] = to_bf16(v0 * sn + v1 * cs);
    }
}

// ---------------------------------------------------------------------------
// Transpose bf16 [2048][1536] -> [1536][2048] via 32x32 LDS tiles.
// ---------------------------------------------------------------------------
__global__ __launch_bounds__(256)
void transpose_bf16(const short* __restrict__ in, short* __restrict__ out)
{
    __shared__ short T[32][33];
    const int k0 = blockIdx.y * 32;
    const int d0 = blockIdx.x * 32;
    const int r = threadIdx.x >> 3;
    const int c4 = (threadIdx.x & 7) * 4;
    short4v v = *(const short4v*)(in + (size_t)(k0 + r) * DIMN + d0 + c4);
    T[r][c4 + 0] = v[0]; T[r][c4 + 1] = v[1];
    T[r][c4 + 2] = v[2]; T[r][c4 + 3] = v[3];
    __syncthreads();
    short4v o;
    o[0] = T[c4 + 0][r]; o[1] = T[c4 + 1][r];
    o[2] = T[c4 + 2][r]; o[3] = T[c4 + 3][r];
    *(short4v*)(out + (size_t)(d0 + r) * SLEN + k0 + c4) = o;
}

// ---------------------------------------------------------------------------
// MFMA flash attention v3 — max-free softmax, occupancy-first decomposition.
// Block = 256 threads (4 waves), 16 q-rows, head = blockIdx.y.
// All 4 waves share the same 16 q-rows; keys split 4-way (512 keys/wave).
// Partials are additive (no max, no rescale); combined once via LDS epilogue.
// LDS: P-region (9.2 KB, in-loop, per-wave) unioned with combine buffers
// (25.5 KB, epilogue) -> 25.5 KB total -> 6 blocks/CU; grid 1536 = 6/CU.
// ---------------------------------------------------------------------------
__global__ __launch_bounds__(256)
void attn_mfma3(const short* __restrict__ Q, const short* __restrict__ K,
                const short* __restrict__ VT, short* __restrict__ O,
                const int* __restrict__ seq_lens)
{
    // union: [0, 9216) = Ps[4][16*72] shorts (loop) ;
    // epilogue: Oc[3][16][132] floats + Lc[3][16] floats = 25536 B
    __shared__ __attribute__((aligned(16))) char smem[25536];
    short* Ps = (short*)smem;
    float* Oc = (float*)smem;                       // [3][16][132]
    float* Lc = (float*)(smem + 3 * 16 * 132 * 4);  // [3][16]

    const int tid = threadIdx.x;
    const int wave = tid >> 6, lane = tid & 63;
    const int quad = lane >> 4, col = lane & 15;
    const int head = blockIdx.y;
    const int row0 = blockIdx.x * 16;
    const int slen = seq_lens[0];
    short* psw = Ps + wave * (16 * 72);

    // persistent Q A-fragments (16 rows), Q pre-scaled by 1/sqrt(HD)
    short8 qf[4];
    #pragma unroll
    for (int kc = 0; kc < 4; ++kc)
        qf[kc] = *(const short8*)(Q + (size_t)(row0 + col) * DIMN
                                  + head * HDIM + kc * 32 + quad * 8);

    f32x4 oacc[8];
    #pragma unroll
    for (int dt = 0; dt < 8; ++dt)
        #pragma unroll
        for (int r = 0; r < 4; ++r) oacc[dt][r] = 0.f;
    float lsum[4] = {0.f, 0.f, 0.f, 0.f};

    const int kbeg = wave * (SLEN / 4);
    for (int kt = kbeg; kt < kbeg + SLEN / 4; kt += 64) {
        // ---- S = Q K^T (16 rows x 64 keys) ----
        f32x4 s[4];
        #pragma unroll
        for (int nt = 0; nt < 4; ++nt)
            #pragma unroll
            for (int r = 0; r < 4; ++r) s[nt][r] = 0.f;

        #pragma unroll
        for (int kc = 0; kc < 4; ++kc) {
            short8 kf[4];
            #pragma unroll
            for (int nt = 0; nt < 4; ++nt)
                kf[nt] = *(const short8*)(K + (size_t)(kt + nt * 16 + col) * DIMN
                                          + head * HDIM + kc * 32 + quad * 8);
            #pragma unroll
            for (int nt = 0; nt < 4; ++nt)
                s[nt] = __builtin_amdgcn_mfma_f32_16x16x32_bf16(qf[kc], kf[nt], s[nt], 0, 0, 0);
        }

        // ---- mask + exp (no max) + per-lane l accumulation + P store ----
        #pragma unroll
        for (int nt = 0; nt < 4; ++nt) {
            const bool masked = (kt + nt * 16 + col >= slen);
            #pragma unroll
            for (int r = 0; r < 4; ++r) {
                float p = masked ? 0.f : __expf(s[nt][r]);
                lsum[r] += p;
                psw[(quad * 4 + r) * 72 + nt * 16 + col] = to_bf16(p);
            }
        }

        // ---- PV: P back as A-frags, V^T B-frags from global ----
        short8 pf[2];
        #pragma unroll
        for (int kc = 0; kc < 2; ++kc)
            pf[kc] = *(const short8*)&psw[col * 72 + kc * 32 + quad * 8];

        #pragma unroll
        for (int dt = 0; dt < 8; ++dt) {
            short8 vf[2];
            #pragma unroll
            for (int kc = 0; kc < 2; ++kc)
                vf[kc] = *(const short8*)(VT + (size_t)(head * HDIM + dt * 16 + col) * SLEN
                                          + kt + kc * 32 + quad * 8);
            #pragma unroll
            for (int kc = 0; kc < 2; ++kc)
                oacc[dt] = __builtin_amdgcn_mfma_f32_16x16x32_bf16(pf[kc], vf[kc], oacc[dt], 0, 0, 0);
        }
    }

    // ---- reduce l across the 16 col lanes (row = quad*4 + r) ----
    #pragma unroll
    for (int r = 0; r < 4; ++r) {
        #pragma unroll
        for (int off = 8; off; off >>= 1) lsum[r] += __shfl_xor(lsum[r], off, 64);
    }

    // ---- 4-way wave combine through LDS (region reused; Ps now dead) ----
    __syncthreads();
    if (wave != 0) {
        float* oc = Oc + (wave - 1) * (16 * 132);
        #pragma unroll
        for (int dt = 0; dt < 8; ++dt)
            #pragma unroll
            for (int r = 0; r < 4; ++r)
                oc[(quad * 4 + r) * 132 + dt * 16 + col] = oacc[dt][r];
        if (col == 0) {
            #pragma unroll
            for (int r = 0; r < 4; ++r) Lc[(wave - 1) * 16 + quad * 4 + r] = lsum[r];
        }
    }
    __syncthreads();
    if (wave == 0) {
        float inv[4];
        #pragma unroll
        for (int r = 0; r < 4; ++r) {
            float l = lsum[r];
            #pragma unroll
            for (int s2 = 0; s2 < 3; ++s2) l += Lc[s2 * 16 + quad * 4 + r];
            inv[r] = 1.0f / l;
        }
        #pragma unroll
        for (int dt = 0; dt < 8; ++dt) {
            #pragma unroll
            for (int r = 0; r < 4; ++r) {
                float v = oacc[dt][r];
                #pragma unroll
                for (int s2 = 0; s2 < 3; ++s2)
                    v += Oc[s2 * (16 * 132) + (quad * 4 + r) * 132 + dt * 16 + col];
                O[(size_t)(row0 + quad * 4 + r) * DIMN + head * HDIM + dt * 16 + col]
                    = to_bf16(v * inv[r]);
            }
        }
    }
}

// ---------------------------------------------------------------------------
extern "C" void kernel_launch(void* const* d_in, const int* in_sizes, int n_in,
                              void* d_out, int out_size, void* d_ws, size_t ws_size,
                              hipStream_t stream)
{
    const float* x     = (const float*)d_in[0];
    const float* freqs = (const float*)d_in[1];
    const float* wq    = (const float*)d_in[2];
    const float* bq    = (const float*)d_in[3];
    const float* wk    = (const float*)d_in[4];
    const float* bk    = (const float*)d_in[5];
    const float* wv    = (const float*)d_in[6];
    const float* bv    = (const float*)d_in[7];
    const float* wo    = (const float*)d_in[8];
    const float* bo    = (const float*)d_in[9];
    const float* gq    = (const float*)d_in[10];
    const float* gk    = (const float*)d_in[11];
    const int* seq_lens   = (const int*)d_in[12];
    const int* grid_sizes = (const int*)d_in[13];
    float* out = (float*)d_out;

    const size_t NX = (size_t)SLEN * DIMN;
    const size_t NW = (size_t)DIMN * DIMN;
    short* xb  = (short*)d_ws;
    short* wqb = xb + NX;
    short* wkb = wqb + NW;
    short* wvb = wkb + NW;
    short* wob = wvb + NW;
    short* qb  = wob + NW;
    short* kb  = qb + NX;
    short* vb  = kb + NX;
    short* vt  = vb + NX;
    short* ob  = vb;          // vb dead after transpose

    cast5<<<dim3(1536, 5), 256, 0, stream>>>(x, wq, wk, wv, wo,
                                             xb, wqb, wkb, wvb, wob,
                                             (int)NX, (int)NW);

    gemm_qkv<<<dim3(3 * DIMN / 128, SLEN / 128), 256, 0, stream>>>(
        xb, wqb, wkb, wvb, bq, bk, bv, qb, kb, vb);

    rms_rope_bf16<<<SLEN, 256, 0, stream>>>(qb, gq, freqs, grid_sizes, 0.08838834764831845f);
    rms_rope_bf16<<<SLEN, 256, 0, stream>>>(kb, gk, freqs, grid_sizes, 1.0f);

    transpose_bf16<<<dim3(DIMN / 32, SLEN / 32), 256, 0, stream>>>(vb, vt);

    attn_mfma3<<<dim3(SLEN / 16, NHEAD), 256, 0, stream>>>(qb, kb, vt, ob, seq_lens);

    gemm_out<<<dim3(DIMN / 128, SLEN / 128), 256, 0, stream>>>(ob, wob, bo, out);
}

// Round 6
// 304.646 us; speedup vs baseline: 24.4139x; 1.3461x over previous
//
#include <hip/hip_runtime.h>
#include <math.h>

#define DIMN 1536
#define NHEAD 12
#define HDIM 128
#define SLEN 2048
#define EPSV 1e-6f

typedef __attribute__((ext_vector_type(8))) short short8;
typedef __attribute__((ext_vector_type(4))) short short4v;
typedef __attribute__((ext_vector_type(4))) float f32x4;

__device__ inline short to_bf16(float f) {
    union { float f; unsigned u; } v; v.f = f;
    unsigned r = (v.u + 0x7FFFu + ((v.u >> 16) & 1u)) >> 16;
    return (short)r;
}
__device__ inline float bf_to_f(short h) {
    union { unsigned u; float f; } v;
    v.u = ((unsigned)(unsigned short)h) << 16;
    return v.f;
}

// ---------------------------------------------------------------------------
// Cast 5 fp32 tensors to bf16 (x + 4 weights), one launch. 8 elems/thread.
// ---------------------------------------------------------------------------
__global__ __launch_bounds__(256)
void cast5(const float* s0, const float* s1, const float* s2,
           const float* s3, const float* s4,
           short* d0, short* d1, short* d2, short* d3, short* d4,
           int n0, int nw)
{
    const float* s; short* d; int n;
    switch (blockIdx.y) {
        case 0: s = s0; d = d0; n = n0; break;
        case 1: s = s1; d = d1; n = nw; break;
        case 2: s = s2; d = d2; n = nw; break;
        case 3: s = s3; d = d3; n = nw; break;
        default: s = s4; d = d4; n = nw; break;
    }
    int idx = (blockIdx.x * 256 + threadIdx.x) * 8;
    if (idx >= n) return;
    float4 a = *(const float4*)(s + idx);
    float4 b = *(const float4*)(s + idx + 4);
    short8 r;
    r[0] = to_bf16(a.x); r[1] = to_bf16(a.y); r[2] = to_bf16(a.z); r[3] = to_bf16(a.w);
    r[4] = to_bf16(b.x); r[5] = to_bf16(b.y); r[6] = to_bf16(b.z); r[7] = to_bf16(b.w);
    *(short8*)(d + idx) = r;
}

// ---------------------------------------------------------------------------
// Fused QKV MFMA GEMM (unchanged from R5).
// ---------------------------------------------------------------------------
__global__ __launch_bounds__(256)
void gemm_qkv(const short* __restrict__ A,
              const short* __restrict__ W0, const short* __restrict__ W1,
              const short* __restrict__ W2,
              const float* __restrict__ b0, const float* __restrict__ b1,
              const float* __restrict__ b2,
              short* __restrict__ Y0, short* __restrict__ Y1,
              short* __restrict__ Y2)
{
    __shared__ short As[128 * 40];
    __shared__ short Bs[128 * 40];

    const int sel = blockIdx.x / (DIMN / 128);
    const int nb  = blockIdx.x % (DIMN / 128);
    const short* W   = (sel == 0) ? W0 : (sel == 1) ? W1 : W2;
    const float* bias= (sel == 0) ? b0 : (sel == 1) ? b1 : b2;
    short* Y         = (sel == 0) ? Y0 : (sel == 1) ? Y1 : Y2;

    const int tid = threadIdx.x;
    const int wave = tid >> 6, lane = tid & 63;
    const int quad = lane >> 4, col = lane & 15;
    const int wm = wave >> 1, wn = wave & 1;
    const int m0 = blockIdx.y * 128, n0 = nb * 128;
    const int srow = tid >> 2;
    const int schunk = (tid & 3) * 8;

    f32x4 acc[4][4];
    #pragma unroll
    for (int i = 0; i < 4; ++i)
        #pragma unroll
        for (int j = 0; j < 4; ++j)
            #pragma unroll
            for (int r = 0; r < 4; ++r) acc[i][j][r] = 0.f;

    for (int kt = 0; kt < DIMN; kt += 32) {
        short8 a0 = *(const short8*)(A + (size_t)(m0 + srow) * DIMN + kt + schunk);
        short8 a1 = *(const short8*)(A + (size_t)(m0 + srow + 64) * DIMN + kt + schunk);
        short8 bb0 = *(const short8*)(W + (size_t)(n0 + srow) * DIMN + kt + schunk);
        short8 bb1 = *(const short8*)(W + (size_t)(n0 + srow + 64) * DIMN + kt + schunk);
        __syncthreads();
        *(short8*)&As[srow * 40 + schunk] = a0;
        *(short8*)&As[(srow + 64) * 40 + schunk] = a1;
        *(short8*)&Bs[srow * 40 + schunk] = bb0;
        *(short8*)&Bs[(srow + 64) * 40 + schunk] = bb1;
        __syncthreads();

        short8 af[4], bf[4];
        #pragma unroll
        for (int mt = 0; mt < 4; ++mt)
            af[mt] = *(const short8*)&As[(wm * 64 + mt * 16 + col) * 40 + quad * 8];
        #pragma unroll
        for (int nt = 0; nt < 4; ++nt)
            bf[nt] = *(const short8*)&Bs[(wn * 64 + nt * 16 + col) * 40 + quad * 8];
        #pragma unroll
        for (int mt = 0; mt < 4; ++mt)
            #pragma unroll
            for (int nt = 0; nt < 4; ++nt)
                acc[mt][nt] = __builtin_amdgcn_mfma_f32_16x16x32_bf16(
                    af[mt], bf[nt], acc[mt][nt], 0, 0, 0);
    }

    #pragma unroll
    for (int mt = 0; mt < 4; ++mt) {
        #pragma unroll
        for (int nt = 0; nt < 4; ++nt) {
            const int n = n0 + wn * 64 + nt * 16 + col;
            const float bb = bias[n];
            #pragma unroll
            for (int r = 0; r < 4; ++r) {
                const int m = m0 + wm * 64 + mt * 16 + quad * 4 + r;
                Y[(size_t)m * DIMN + n] = to_bf16(acc[mt][nt][r] + bb);
            }
        }
    }
}

// ---------------------------------------------------------------------------
// Output-projection GEMM, fp32 out (unchanged from R5).
// ---------------------------------------------------------------------------
__global__ __launch_bounds__(256)
void gemm_out(const short* __restrict__ A, const short* __restrict__ W,
              const float* __restrict__ bias, float* __restrict__ Yf)
{
    __shared__ short As[128 * 40];
    __shared__ short Bs[128 * 40];

    const int tid = threadIdx.x;
    const int wave = tid >> 6, lane = tid & 63;
    const int quad = lane >> 4, col = lane & 15;
    const int wm = wave >> 1, wn = wave & 1;
    const int m0 = blockIdx.y * 128, n0 = blockIdx.x * 128;
    const int srow = tid >> 2;
    const int schunk = (tid & 3) * 8;

    f32x4 acc[4][4];
    #pragma unroll
    for (int i = 0; i < 4; ++i)
        #pragma unroll
        for (int j = 0; j < 4; ++j)
            #pragma unroll
            for (int r = 0; r < 4; ++r) acc[i][j][r] = 0.f;

    for (int kt = 0; kt < DIMN; kt += 32) {
        short8 a0 = *(const short8*)(A + (size_t)(m0 + srow) * DIMN + kt + schunk);
        short8 a1 = *(const short8*)(A + (size_t)(m0 + srow + 64) * DIMN + kt + schunk);
        short8 bb0 = *(const short8*)(W + (size_t)(n0 + srow) * DIMN + kt + schunk);
        short8 bb1 = *(const short8*)(W + (size_t)(n0 + srow + 64) * DIMN + kt + schunk);
        __syncthreads();
        *(short8*)&As[srow * 40 + schunk] = a0;
        *(short8*)&As[(srow + 64) * 40 + schunk] = a1;
        *(short8*)&Bs[srow * 40 + schunk] = bb0;
        *(short8*)&Bs[(srow + 64) * 40 + schunk] = bb1;
        __syncthreads();

        short8 af[4], bf[4];
        #pragma unroll
        for (int mt = 0; mt < 4; ++mt)
            af[mt] = *(const short8*)&As[(wm * 64 + mt * 16 + col) * 40 + quad * 8];
        #pragma unroll
        for (int nt = 0; nt < 4; ++nt)
            bf[nt] = *(const short8*)&Bs[(wn * 64 + nt * 16 + col) * 40 + quad * 8];
        #pragma unroll
        for (int mt = 0; mt < 4; ++mt)
            #pragma unroll
            for (int nt = 0; nt < 4; ++nt)
                acc[mt][nt] = __builtin_amdgcn_mfma_f32_16x16x32_bf16(
                    af[mt], bf[nt], acc[mt][nt], 0, 0, 0);
    }

    #pragma unroll
    for (int mt = 0; mt < 4; ++mt) {
        #pragma unroll
        for (int nt = 0; nt < 4; ++nt) {
            const int n = n0 + wn * 64 + nt * 16 + col;
            const float bb = bias[n];
            #pragma unroll
            for (int r = 0; r < 4; ++r) {
                const int m = m0 + wm * 64 + mt * 16 + quad * 4 + r;
                Yf[(size_t)m * DIMN + n] = acc[mt][nt][r] + bb;
            }
        }
    }
}

// ---------------------------------------------------------------------------
// RMSNorm + RoPE for Q, row layout, in place (1/sqrt(HD) folded).
// ---------------------------------------------------------------------------
__global__ __launch_bounds__(256)
void rms_rope_q(short* __restrict__ buf, const float* __restrict__ g,
                const float* __restrict__ freqs, const int* __restrict__ grid_sizes)
{
    const int s = blockIdx.x;
    const int tid = threadIdx.x;
    short* row = buf + (size_t)s * DIMN;

    float ss = 0.f;
    if (tid < 192) {
        short8 v = *(const short8*)(row + tid * 8);
        #pragma unroll
        for (int j = 0; j < 8; ++j) { float f = bf_to_f(v[j]); ss += f * f; }
    }
    #pragma unroll
    for (int off = 32; off; off >>= 1) ss += __shfl_down(ss, off, 64);

    __shared__ float red[4];
    __shared__ float s_scale;
    if ((tid & 63) == 0) red[tid >> 6] = ss;
    __syncthreads();
    if (tid == 0) {
        float t = red[0] + red[1] + red[2] + red[3];
        s_scale = rsqrtf(t / (float)DIMN + EPSV) * 0.08838834764831845f;
    }
    __syncthreads();
    const float scale = s_scale;

    const int h = grid_sizes[1], w = grid_sizes[2];
    const int fi = s / (h * w);
    const int hi = (s / w) % h;
    const int wi = s % w;

    for (int p = tid; p < NHEAD * 64; p += 256) {
        const int n = p >> 6;
        const int d = p & 63;
        const int idx = (d < 22) ? fi : ((d < 43) ? hi : wi);
        const float ang = freqs[idx * 64 + d];
        const float cs = cosf(ang), sn = sinf(ang);
        const int base = n * HDIM + 2 * d;
        const float v0 = bf_to_f(row[base]) * scale * g[base];
        const float v1 = bf_to_f(row[base + 1]) * scale * g[base + 1];
        row[base]     = to_bf16(v0 * cs - v1 * sn);
        row[base + 1] = to_bf16(v0 * sn + v1 * cs);
    }
}

// ---------------------------------------------------------------------------
// RMSNorm + RoPE for K, writing MFMA-B-fragment-swizzled Kp.
// Kp chunk (head n, kb=key/16, kc=dim/32): 1 KB; lane quad*16+col holds
// K[key=kb*16+col][n*128 + kc*32 + quad*8 .. +8].  Thread u<192 handles
// (n=u/16, octet o=u%16): dims o*8..o*8+7 = rope pairs o*4..o*4+3.
// ---------------------------------------------------------------------------
__global__ __launch_bounds__(256)
void rms_rope_k_pack(const short* __restrict__ buf, short* __restrict__ Kp,
                     const float* __restrict__ g, const float* __restrict__ freqs,
                     const int* __restrict__ grid_sizes)
{
    const int s = blockIdx.x;
    const int tid = threadIdx.x;
    const short* row = buf + (size_t)s * DIMN;

    float ss = 0.f;
    if (tid < 192) {
        short8 v = *(const short8*)(row + tid * 8);
        #pragma unroll
        for (int j = 0; j < 8; ++j) { float f = bf_to_f(v[j]); ss += f * f; }
    }
    #pragma unroll
    for (int off = 32; off; off >>= 1) ss += __shfl_down(ss, off, 64);

    __shared__ float red[4];
    __shared__ float s_scale;
    if ((tid & 63) == 0) red[tid >> 6] = ss;
    __syncthreads();
    if (tid == 0) {
        float t = red[0] + red[1] + red[2] + red[3];
        s_scale = rsqrtf(t / (float)DIMN + EPSV);
    }
    __syncthreads();
    const float scale = s_scale;

    const int h = grid_sizes[1], w = grid_sizes[2];
    const int fi = s / (h * w);
    const int hi = (s / w) % h;
    const int wi = s % w;

    if (tid < 192) {
        const int n = tid >> 4;
        const int o = tid & 15;
        short8 outv;
        #pragma unroll
        for (int pp = 0; pp < 4; ++pp) {
            const int pd = o * 4 + pp;                    // rope pair index 0..63
            const int idx = (pd < 22) ? fi : ((pd < 43) ? hi : wi);
            const float ang = freqs[idx * 64 + pd];
            const float cs = cosf(ang), sn = sinf(ang);
            const int base = n * HDIM + 2 * pd;
            const float v0 = bf_to_f(row[base]) * scale * g[base];
            const float v1 = bf_to_f(row[base + 1]) * scale * g[base + 1];
            outv[pp * 2]     = to_bf16(v0 * cs - v1 * sn);
            outv[pp * 2 + 1] = to_bf16(v0 * sn + v1 * cs);
        }
        const int kb = s >> 4, col = s & 15;
        const int kc = o >> 2, quad = o & 3;
        const size_t addr = ((((size_t)(n * 128 + kb) * 4 + kc) * 64) + quad * 16 + col) * 8;
        *(short8*)(Kp + addr) = outv;
    }
}

// ---------------------------------------------------------------------------
// Pack V into MFMA-B-fragment-swizzled Vp.
// Vp chunk (head, kt64=key/64, dt=d/16, kc=(key%64)/32): 1 KB; lane q*16+c
// holds V[key = kt64*64 + kc*32 + q*8 .. +8][head*128 + dt*16 + c].
// One block per (head, kt64): stages a 64x128 tile in LDS then scatters.
// ---------------------------------------------------------------------------
__global__ __launch_bounds__(256)
void pack_v(const short* __restrict__ V, short* __restrict__ Vp)
{
    __shared__ short T[64 * 136];    // pitch 136 elems (272 B)
    const int head = blockIdx.x;
    const int kt64 = blockIdx.y;
    const int tid = threadIdx.x;

    // stage: coalesced reads, 4 passes of 16 rows
    const int r0 = tid >> 4, c16 = (tid & 15) * 8;
    #pragma unroll
    for (int p = 0; p < 4; ++p) {
        const int r = r0 + p * 16;
        short8 v = *(const short8*)(V + (size_t)(kt64 * 64 + r) * DIMN + head * HDIM + c16);
        *(short8*)&T[r * 136 + c16] = v;
    }
    __syncthreads();

    // scatter: 1024 lane-slots, 4 per thread
    #pragma unroll
    for (int p = 0; p < 4; ++p) {
        const int slot = tid + p * 256;
        const int c = slot >> 6;          // chunk 0..15 = dt*2 + kc
        const int L = slot & 63;
        const int dt = c >> 1, kc = c & 1;
        const int quad = L >> 4, col = L & 15;
        short8 o;
        #pragma unroll
        for (int j = 0; j < 8; ++j)
            o[j] = T[(kc * 32 + quad * 8 + j) * 136 + dt * 16 + col];
        const size_t addr = ((((size_t)(head * 32 + kt64) * 8 + dt) * 2 + kc) * 64 + L) * 8;
        *(short8*)(Vp + addr) = o;
    }
}

// ---------------------------------------------------------------------------
// MFMA flash attention v4 — max-free softmax + fragment-swizzled K/V.
// Block = 256 threads (4 waves), 16 q-rows; keys split 4-way across waves.
// All hot-loop global loads are fully coalesced 1 KB streaming reads.
// ---------------------------------------------------------------------------
__global__ __launch_bounds__(256)
void attn_mfma4(const short* __restrict__ Q, const short* __restrict__ Kp,
                const short* __restrict__ Vp, short* __restrict__ O,
                const int* __restrict__ seq_lens)
{
    // union: loop: Ps[4][16*72] shorts (9216 B); epilogue: Oc[3][16][132] + Lc[3][16]
    __shared__ __attribute__((aligned(16))) char smem[25536];
    short* Ps = (short*)smem;
    float* Oc = (float*)smem;
    float* Lc = (float*)(smem + 3 * 16 * 132 * 4);

    const int tid = threadIdx.x;
    const int wave = tid >> 6, lane = tid & 63;
    const int quad = lane >> 4, col = lane & 15;
    const int head = blockIdx.y;
    const int row0 = blockIdx.x * 16;
    const int slen = seq_lens[0];
    short* psw = Ps + wave * (16 * 72);

    // persistent Q A-fragments (16 rows), Q pre-scaled by 1/sqrt(HD)
    short8 qf[4];
    #pragma unroll
    for (int kc = 0; kc < 4; ++kc)
        qf[kc] = *(const short8*)(Q + (size_t)(row0 + col) * DIMN
                                  + head * HDIM + kc * 32 + quad * 8);

    f32x4 oacc[8];
    #pragma unroll
    for (int dt = 0; dt < 8; ++dt)
        #pragma unroll
        for (int r = 0; r < 4; ++r) oacc[dt][r] = 0.f;
    float lsum[4] = {0.f, 0.f, 0.f, 0.f};

    const int kbeg = wave * (SLEN / 4);
    for (int kt = kbeg; kt < kbeg + SLEN / 4; kt += 64) {
        // ---- S = Q K^T (16 rows x 64 keys); Kp chunks are coalesced ----
        f32x4 s[4];
        #pragma unroll
        for (int nt = 0; nt < 4; ++nt)
            #pragma unroll
            for (int r = 0; r < 4; ++r) s[nt][r] = 0.f;

        const int kb0 = kt >> 4;
        #pragma unroll
        for (int kc = 0; kc < 4; ++kc) {
            short8 kf[4];
            #pragma unroll
            for (int nt = 0; nt < 4; ++nt)
                kf[nt] = *(const short8*)(Kp +
                    ((((size_t)(head * 128 + kb0 + nt) * 4 + kc) * 64) + lane) * 8);
            #pragma unroll
            for (int nt = 0; nt < 4; ++nt)
                s[nt] = __builtin_amdgcn_mfma_f32_16x16x32_bf16(qf[kc], kf[nt], s[nt], 0, 0, 0);
        }

        // ---- mask + exp (no max) + per-lane l accumulation + P store ----
        #pragma unroll
        for (int nt = 0; nt < 4; ++nt) {
            const bool masked = (kt + nt * 16 + col >= slen);
            #pragma unroll
            for (int r = 0; r < 4; ++r) {
                float p = masked ? 0.f : __expf(s[nt][r]);
                lsum[r] += p;
                psw[(quad * 4 + r) * 72 + nt * 16 + col] = to_bf16(p);
            }
        }

        // ---- PV: P back as A-frags, Vp chunks coalesced ----
        short8 pf[2];
        #pragma unroll
        for (int kc = 0; kc < 2; ++kc)
            pf[kc] = *(const short8*)&psw[col * 72 + kc * 32 + quad * 8];

        const size_t vbase = ((size_t)(head * 32 + (kt >> 6)) * 16) * 512;  // 16 chunks x 512 elems
        #pragma unroll
        for (int dt = 0; dt < 8; ++dt) {
            short8 vf[2];
            #pragma unroll
            for (int kc = 0; kc < 2; ++kc)
                vf[kc] = *(const short8*)(Vp + vbase + ((size_t)(dt * 2 + kc) * 64 + lane) * 8);
            #pragma unroll
            for (int kc = 0; kc < 2; ++kc)
                oacc[dt] = __builtin_amdgcn_mfma_f32_16x16x32_bf16(pf[kc], vf[kc], oacc[dt], 0, 0, 0);
        }
    }

    // ---- reduce l across the 16 col lanes ----
    #pragma unroll
    for (int r = 0; r < 4; ++r) {
        #pragma unroll
        for (int off = 8; off; off >>= 1) lsum[r] += __shfl_xor(lsum[r], off, 64);
    }

    // ---- 4-way wave combine through LDS (Ps dead) ----
    __syncthreads();
    if (wave != 0) {
        float* oc = Oc + (wave - 1) * (16 * 132);
        #pragma unroll
        for (int dt = 0; dt < 8; ++dt)
            #pragma unroll
            for (int r = 0; r < 4; ++r)
                oc[(quad * 4 + r) * 132 + dt * 16 + col] = oacc[dt][r];
        if (col == 0) {
            #pragma unroll
            for (int r = 0; r < 4; ++r) Lc[(wave - 1) * 16 + quad * 4 + r] = lsum[r];
        }
    }
    __syncthreads();
    if (wave == 0) {
        float inv[4];
        #pragma unroll
        for (int r = 0; r < 4; ++r) {
            float l = lsum[r];
            #pragma unroll
            for (int s2 = 0; s2 < 3; ++s2) l += Lc[s2 * 16 + quad * 4 + r];
            inv[r] = 1.0f / l;
        }
        #pragma unroll
        for (int dt = 0; dt < 8; ++dt) {
            #pragma unroll
            for (int r = 0; r < 4; ++r) {
                float v = oacc[dt][r];
                #pragma unroll
                for (int s2 = 0; s2 < 3; ++s2)
                    v += Oc[s2 * (16 * 132) + (quad * 4 + r) * 132 + dt * 16 + col];
                O[(size_t)(row0 + quad * 4 + r) * DIMN + head * HDIM + dt * 16 + col]
                    = to_bf16(v * inv[r]);
            }
        }
    }
}

// ---------------------------------------------------------------------------
extern "C" void kernel_launch(void* const* d_in, const int* in_sizes, int n_in,
                              void* d_out, int out_size, void* d_ws, size_t ws_size,
                              hipStream_t stream)
{
    const float* x     = (const float*)d_in[0];
    const float* freqs = (const float*)d_in[1];
    const float* wq    = (const float*)d_in[2];
    const float* bq    = (const float*)d_in[3];
    const float* wk    = (const float*)d_in[4];
    const float* bk    = (const float*)d_in[5];
    const float* wv    = (const float*)d_in[6];
    const float* bv    = (const float*)d_in[7];
    const float* wo    = (const float*)d_in[8];
    const float* bo    = (const float*)d_in[9];
    const float* gq    = (const float*)d_in[10];
    const float* gk    = (const float*)d_in[11];
    const int* seq_lens   = (const int*)d_in[12];
    const int* grid_sizes = (const int*)d_in[13];
    float* out = (float*)d_out;

    const size_t NX = (size_t)SLEN * DIMN;
    const size_t NW = (size_t)DIMN * DIMN;
    short* xb  = (short*)d_ws;
    short* wqb = xb + NX;
    short* wkb = wqb + NW;
    short* wvb = wkb + NW;
    short* wob = wvb + NW;
    short* qb  = wob + NW;
    short* kb  = qb + NX;
    short* vb  = kb + NX;
    short* vp  = vb + NX;
    short* kp  = vp + NX;
    short* ob  = vb;          // vb dead after pack_v

    cast5<<<dim3(1536, 5), 256, 0, stream>>>(x, wq, wk, wv, wo,
                                             xb, wqb, wkb, wvb, wob,
                                             (int)NX, (int)NW);

    gemm_qkv<<<dim3(3 * DIMN / 128, SLEN / 128), 256, 0, stream>>>(
        xb, wqb, wkb, wvb, bq, bk, bv, qb, kb, vb);

    rms_rope_q<<<SLEN, 256, 0, stream>>>(qb, gq, freqs, grid_sizes);
    rms_rope_k_pack<<<SLEN, 256, 0, stream>>>(kb, kp, gk, freqs, grid_sizes);
    pack_v<<<dim3(NHEAD, SLEN / 64), 256, 0, stream>>>(vb, vp);

    attn_mfma4<<<dim3(SLEN / 16, NHEAD), 256, 0, stream>>>(qb, kp, vp, ob, seq_lens);

    gemm_out<<<dim3(DIMN / 128, SLEN / 128), 256, 0, stream>>>(ob, wob, bo, out);
}

// Round 7
// 288.334 us; speedup vs baseline: 25.7951x; 1.0566x over previous
//
#include <hip/hip_runtime.h>
#include <math.h>

#define DIMN 1536
#define NHEAD 12
#define HDIM 128
#define SLEN 2048
#define EPSV 1e-6f

typedef __attribute__((ext_vector_type(8))) short short8;
typedef __attribute__((ext_vector_type(4))) short short4v;
typedef __attribute__((ext_vector_type(4))) float f32x4;

typedef __attribute__((address_space(1))) const void gvoid_t;
typedef __attribute__((address_space(3))) void lvoid_t;

__device__ __forceinline__ void gload_lds16(const void* g, void* l) {
    __builtin_amdgcn_global_load_lds((gvoid_t*)g, (lvoid_t*)l, 16, 0, 0);
}

__device__ inline short to_bf16(float f) {
    union { float f; unsigned u; } v; v.f = f;
    unsigned r = (v.u + 0x7FFFu + ((v.u >> 16) & 1u)) >> 16;
    return (short)r;
}
__device__ inline float bf_to_f(short h) {
    union { unsigned u; float f; } v;
    v.u = ((unsigned)(unsigned short)h) << 16;
    return v.f;
}

// chunk swizzle: decorrelates the 8-elem k-chunk slot with the tile row so
// fragment ds_read_b128 spreads over all 32 banks (2-way pairs = free).
__device__ __forceinline__ int swz(int row, int c) {
    return c ^ (row & 3) ^ ((row >> 2) & 3);
}

// ---------------------------------------------------------------------------
// Cast 5 fp32 tensors to bf16 (x + 4 weights), one launch.
// ---------------------------------------------------------------------------
__global__ __launch_bounds__(256)
void cast5(const float* s0, const float* s1, const float* s2,
           const float* s3, const float* s4,
           short* d0, short* d1, short* d2, short* d3, short* d4,
           int n0, int nw)
{
    const float* s; short* d; int n;
    switch (blockIdx.y) {
        case 0: s = s0; d = d0; n = n0; break;
        case 1: s = s1; d = d1; n = nw; break;
        case 2: s = s2; d = d2; n = nw; break;
        case 3: s = s3; d = d3; n = nw; break;
        default: s = s4; d = d4; n = nw; break;
    }
    int idx = (blockIdx.x * 256 + threadIdx.x) * 8;
    if (idx >= n) return;
    float4 a = *(const float4*)(s + idx);
    float4 b = *(const float4*)(s + idx + 4);
    short8 r;
    r[0] = to_bf16(a.x); r[1] = to_bf16(a.y); r[2] = to_bf16(a.z); r[3] = to_bf16(a.w);
    r[4] = to_bf16(b.x); r[5] = to_bf16(b.y); r[6] = to_bf16(b.z); r[7] = to_bf16(b.w);
    *(short8*)(d + idx) = r;
}

// ---------------------------------------------------------------------------
// m97-style MFMA GEMM core: 128x128 tile, BK=32, global_load_lds width-16
// staging into linear (lane-order) LDS, XOR-swizzled k-chunk placement.
// ---------------------------------------------------------------------------
template<bool F32OUT>
__device__ __forceinline__ void gemm_core(const short* __restrict__ A,
    const short* __restrict__ W, const float* __restrict__ bias,
    short* __restrict__ Yh, float* __restrict__ Yf,
    int m0, int n0, int N, int K, short* As, short* Bs)
{
    const int tid = threadIdx.x;
    const int wave = tid >> 6, lane = tid & 63;
    const int quad = lane >> 4, col = lane & 15;
    const int wm = wave >> 1, wn = wave & 1;
    const int sr = tid >> 2;        // row within 64-row half of the tile
    const int sc = tid & 3;         // LDS chunk slot

    f32x4 acc[4][4];
    #pragma unroll
    for (int i = 0; i < 4; ++i)
        #pragma unroll
        for (int j = 0; j < 4; ++j)
            #pragma unroll
            for (int r = 0; r < 4; ++r) acc[i][j][r] = 0.f;

    for (int kt = 0; kt < K; kt += 32) {
        __syncthreads();            // prior frags consumed
        #pragma unroll
        for (int i = 0; i < 2; ++i) {
            const int row = i * 64 + sr;
            const int ca = swz(row, sc);
            gload_lds16(A + (size_t)(m0 + row) * K + kt + ca * 8, As + i * 2048 + tid * 8);
        }
        #pragma unroll
        for (int i = 0; i < 2; ++i) {
            const int row = i * 64 + sr;
            const int cb = swz(row, sc);
            gload_lds16(W + (size_t)(n0 + row) * K + kt + cb * 8, Bs + i * 2048 + tid * 8);
        }
        __syncthreads();            // drains vmcnt -> data visible

        short8 af[4], bf[4];
        #pragma unroll
        for (int mt = 0; mt < 4; ++mt) {
            const int row = wm * 64 + mt * 16 + col;
            af[mt] = *(const short8*)&As[row * 32 + swz(row, quad) * 8];
        }
        #pragma unroll
        for (int nt = 0; nt < 4; ++nt) {
            const int row = wn * 64 + nt * 16 + col;
            bf[nt] = *(const short8*)&Bs[row * 32 + swz(row, quad) * 8];
        }
        #pragma unroll
        for (int mt = 0; mt < 4; ++mt)
            #pragma unroll
            for (int nt = 0; nt < 4; ++nt)
                acc[mt][nt] = __builtin_amdgcn_mfma_f32_16x16x32_bf16(
                    af[mt], bf[nt], acc[mt][nt], 0, 0, 0);
    }

    #pragma unroll
    for (int mt = 0; mt < 4; ++mt) {
        #pragma unroll
        for (int nt = 0; nt < 4; ++nt) {
            const int n = n0 + wn * 64 + nt * 16 + col;
            const float bb = bias[n];
            #pragma unroll
            for (int r = 0; r < 4; ++r) {
                const int m = m0 + wm * 64 + mt * 16 + quad * 4 + r;
                const float v = acc[mt][nt][r] + bb;
                if (F32OUT) Yf[(size_t)m * N + n] = v;
                else        Yh[(size_t)m * N + n] = to_bf16(v);
            }
        }
    }
}

__global__ __launch_bounds__(256)
void gemm_qkv(const short* __restrict__ A,
              const short* __restrict__ W0, const short* __restrict__ W1,
              const short* __restrict__ W2,
              const float* __restrict__ b0, const float* __restrict__ b1,
              const float* __restrict__ b2,
              short* __restrict__ Y0, short* __restrict__ Y1,
              short* __restrict__ Y2)
{
    __shared__ __attribute__((aligned(16))) short As[128 * 32];
    __shared__ __attribute__((aligned(16))) short Bs[128 * 32];
    const int sel = blockIdx.x / (DIMN / 128);
    const int nb  = blockIdx.x % (DIMN / 128);
    const short* W    = (sel == 0) ? W0 : (sel == 1) ? W1 : W2;
    const float* bias = (sel == 0) ? b0 : (sel == 1) ? b1 : b2;
    short* Y          = (sel == 0) ? Y0 : (sel == 1) ? Y1 : Y2;
    gemm_core<false>(A, W, bias, Y, nullptr, blockIdx.y * 128, nb * 128,
                     DIMN, DIMN, As, Bs);
}

__global__ __launch_bounds__(256)
void gemm_out(const short* __restrict__ A, const short* __restrict__ W,
              const float* __restrict__ bias, float* __restrict__ Yf)
{
    __shared__ __attribute__((aligned(16))) short As[128 * 32];
    __shared__ __attribute__((aligned(16))) short Bs[128 * 32];
    gemm_core<true>(A, W, bias, nullptr, Yf, blockIdx.y * 128, blockIdx.x * 128,
                    DIMN, DIMN, As, Bs);
}

// ---------------------------------------------------------------------------
// RMSNorm + RoPE for Q, row layout, in place (1/sqrt(HD) folded).
// ---------------------------------------------------------------------------
__global__ __launch_bounds__(256)
void rms_rope_q(short* __restrict__ buf, const float* __restrict__ g,
                const float* __restrict__ freqs, const int* __restrict__ grid_sizes)
{
    const int s = blockIdx.x;
    const int tid = threadIdx.x;
    short* row = buf + (size_t)s * DIMN;

    float ss = 0.f;
    if (tid < 192) {
        short8 v = *(const short8*)(row + tid * 8);
        #pragma unroll
        for (int j = 0; j < 8; ++j) { float f = bf_to_f(v[j]); ss += f * f; }
    }
    #pragma unroll
    for (int off = 32; off; off >>= 1) ss += __shfl_down(ss, off, 64);

    __shared__ float red[4];
    __shared__ float s_scale;
    if ((tid & 63) == 0) red[tid >> 6] = ss;
    __syncthreads();
    if (tid == 0) {
        float t = red[0] + red[1] + red[2] + red[3];
        s_scale = rsqrtf(t / (float)DIMN + EPSV) * 0.08838834764831845f;
    }
    __syncthreads();
    const float scale = s_scale;

    const int h = grid_sizes[1], w = grid_sizes[2];
    const int fi = s / (h * w);
    const int hi = (s / w) % h;
    const int wi = s % w;

    for (int p = tid; p < NHEAD * 64; p += 256) {
        const int n = p >> 6;
        const int d = p & 63;
        const int idx = (d < 22) ? fi : ((d < 43) ? hi : wi);
        const float ang = freqs[idx * 64 + d];
        const float cs = cosf(ang), sn = sinf(ang);
        const int base = n * HDIM + 2 * d;
        const float v0 = bf_to_f(row[base]) * scale * g[base];
        const float v1 = bf_to_f(row[base + 1]) * scale * g[base + 1];
        row[base]     = to_bf16(v0 * cs - v1 * sn);
        row[base + 1] = to_bf16(v0 * sn + v1 * cs);
    }
}

// ---------------------------------------------------------------------------
// RMSNorm + RoPE for K, writing MFMA-B-fragment-swizzled Kp (as in R6).
// ---------------------------------------------------------------------------
__global__ __launch_bounds__(256)
void rms_rope_k_pack(const short* __restrict__ buf, short* __restrict__ Kp,
                     const float* __restrict__ g, const float* __restrict__ freqs,
                     const int* __restrict__ grid_sizes)
{
    const int s = blockIdx.x;
    const int tid = threadIdx.x;
    const short* row = buf + (size_t)s * DIMN;

    float ss = 0.f;
    if (tid < 192) {
        short8 v = *(const short8*)(row + tid * 8);
        #pragma unroll
        for (int j = 0; j < 8; ++j) { float f = bf_to_f(v[j]); ss += f * f; }
    }
    #pragma unroll
    for (int off = 32; off; off >>= 1) ss += __shfl_down(ss, off, 64);

    __shared__ float red[4];
    __shared__ float s_scale;
    if ((tid & 63) == 0) red[tid >> 6] = ss;
    __syncthreads();
    if (tid == 0) {
        float t = red[0] + red[1] + red[2] + red[3];
        s_scale = rsqrtf(t / (float)DIMN + EPSV);
    }
    __syncthreads();
    const float scale = s_scale;

    const int h = grid_sizes[1], w = grid_sizes[2];
    const int fi = s / (h * w);
    const int hi = (s / w) % h;
    const int wi = s % w;

    if (tid < 192) {
        const int n = tid >> 4;
        const int o = tid & 15;
        short8 outv;
        #pragma unroll
        for (int pp = 0; pp < 4; ++pp) {
            const int pd = o * 4 + pp;
            const int idx = (pd < 22) ? fi : ((pd < 43) ? hi : wi);
            const float ang = freqs[idx * 64 + pd];
            const float cs = cosf(ang), sn = sinf(ang);
            const int base = n * HDIM + 2 * pd;
            const float v0 = bf_to_f(row[base]) * scale * g[base];
            const float v1 = bf_to_f(row[base + 1]) * scale * g[base + 1];
            outv[pp * 2]     = to_bf16(v0 * cs - v1 * sn);
            outv[pp * 2 + 1] = to_bf16(v0 * sn + v1 * cs);
        }
        const int kb = s >> 4, col = s & 15;
        const int kc = o >> 2, quad = o & 3;
        const size_t addr = ((((size_t)(n * 128 + kb) * 4 + kc) * 64) + quad * 16 + col) * 8;
        *(short8*)(Kp + addr) = outv;
    }
}

// ---------------------------------------------------------------------------
// Pack V into MFMA-B-fragment-swizzled Vp (as in R6).
// ---------------------------------------------------------------------------
__global__ __launch_bounds__(256)
void pack_v(const short* __restrict__ V, short* __restrict__ Vp)
{
    __shared__ short T[64 * 136];
    const int head = blockIdx.x;
    const int kt64 = blockIdx.y;
    const int tid = threadIdx.x;

    const int r0 = tid >> 4, c16 = (tid & 15) * 8;
    #pragma unroll
    for (int p = 0; p < 4; ++p) {
        const int r = r0 + p * 16;
        short8 v = *(const short8*)(V + (size_t)(kt64 * 64 + r) * DIMN + head * HDIM + c16);
        *(short8*)&T[r * 136 + c16] = v;
    }
    __syncthreads();

    #pragma unroll
    for (int p = 0; p < 4; ++p) {
        const int slot = tid + p * 256;
        const int c = slot >> 6;
        const int L = slot & 63;
        const int dt = c >> 1, kc = c & 1;
        const int quad = L >> 4, col = L & 15;
        short8 o;
        #pragma unroll
        for (int j = 0; j < 8; ++j)
            o[j] = T[(kc * 32 + quad * 8 + j) * 136 + dt * 16 + col];
        const size_t addr = ((((size_t)(head * 32 + kt64) * 8 + dt) * 2 + kc) * 64 + L) * 8;
        *(short8*)(Vp + addr) = o;
    }
}

// ---------------------------------------------------------------------------
// MFMA flash attention v5 — max-free softmax, fragment-swizzled K/V,
// 32 q-rows per block (2 A-frags) to halve K/V L2 traffic per output.
// 256 threads (4 waves); keys split 4-way across waves; one combine barrier.
// ---------------------------------------------------------------------------
__global__ __launch_bounds__(256)
void attn_mfma5(const short* __restrict__ Q, const short* __restrict__ Kp,
                const short* __restrict__ Vp, short* __restrict__ O,
                const int* __restrict__ seq_lens)
{
    // union: loop: Ps[4][32*72] shorts (18432 B);
    // epilogue: Oc[3][32*132] f32 (50688 B) + Lc[3][32] f32 (384 B)
    __shared__ __attribute__((aligned(16))) char smem[51072];
    short* Ps = (short*)smem;
    float* Oc = (float*)smem;
    float* Lc = (float*)(smem + 3 * 32 * 132 * 4);

    const int tid = threadIdx.x;
    const int wave = tid >> 6, lane = tid & 63;
    const int quad = lane >> 4, col = lane & 15;
    const int head = blockIdx.y;
    const int row0 = blockIdx.x * 32;
    const int slen = seq_lens[0];
    short* psw = Ps + wave * (32 * 72);

    short8 qf[2][4];
    #pragma unroll
    for (int mt = 0; mt < 2; ++mt)
        #pragma unroll
        for (int kc = 0; kc < 4; ++kc)
            qf[mt][kc] = *(const short8*)(Q + (size_t)(row0 + mt * 16 + col) * DIMN
                                          + head * HDIM + kc * 32 + quad * 8);

    f32x4 oacc[2][8];
    #pragma unroll
    for (int mt = 0; mt < 2; ++mt)
        #pragma unroll
        for (int dt = 0; dt < 8; ++dt)
            #pragma unroll
            for (int r = 0; r < 4; ++r) oacc[mt][dt][r] = 0.f;
    float lsum[2][4] = {};

    const int kbeg = wave * (SLEN / 4);
    for (int kt = kbeg; kt < kbeg + SLEN / 4; kt += 64) {
        const int kb0 = kt >> 4;
        f32x4 s[2][4];
        #pragma unroll
        for (int mt = 0; mt < 2; ++mt)
            #pragma unroll
            for (int nt = 0; nt < 4; ++nt)
                #pragma unroll
                for (int r = 0; r < 4; ++r) s[mt][nt][r] = 0.f;

        #pragma unroll
        for (int kc = 0; kc < 4; ++kc) {
            short8 kf[4];
            #pragma unroll
            for (int nt = 0; nt < 4; ++nt)
                kf[nt] = *(const short8*)(Kp +
                    ((((size_t)(head * 128 + kb0 + nt) * 4 + kc) * 64) + lane) * 8);
            #pragma unroll
            for (int mt = 0; mt < 2; ++mt)
                #pragma unroll
                for (int nt = 0; nt < 4; ++nt)
                    s[mt][nt] = __builtin_amdgcn_mfma_f32_16x16x32_bf16(
                        qf[mt][kc], kf[nt], s[mt][nt], 0, 0, 0);
        }

        #pragma unroll
        for (int mt = 0; mt < 2; ++mt)
            #pragma unroll
            for (int nt = 0; nt < 4; ++nt) {
                const bool masked = (kt + nt * 16 + col >= slen);
                #pragma unroll
                for (int r = 0; r < 4; ++r) {
                    float p = masked ? 0.f : __expf(s[mt][nt][r]);
                    lsum[mt][r] += p;
                    psw[(mt * 16 + quad * 4 + r) * 72 + nt * 16 + col] = to_bf16(p);
                }
            }

        short8 pf[2][2];
        #pragma unroll
        for (int mt = 0; mt < 2; ++mt)
            #pragma unroll
            for (int kc = 0; kc < 2; ++kc)
                pf[mt][kc] = *(const short8*)&psw[(mt * 16 + col) * 72 + kc * 32 + quad * 8];

        const size_t vbase = ((size_t)(head * 32 + (kt >> 6)) * 16) * 512;
        #pragma unroll
        for (int dt = 0; dt < 8; ++dt) {
            short8 vf[2];
            #pragma unroll
            for (int kc = 0; kc < 2; ++kc)
                vf[kc] = *(const short8*)(Vp + vbase + ((size_t)(dt * 2 + kc) * 64 + lane) * 8);
            #pragma unroll
            for (int mt = 0; mt < 2; ++mt)
                #pragma unroll
                for (int kc = 0; kc < 2; ++kc)
                    oacc[mt][dt] = __builtin_amdgcn_mfma_f32_16x16x32_bf16(
                        pf[mt][kc], vf[kc], oacc[mt][dt], 0, 0, 0);
        }
    }

    #pragma unroll
    for (int mt = 0; mt < 2; ++mt)
        #pragma unroll
        for (int r = 0; r < 4; ++r) {
            #pragma unroll
            for (int off = 8; off; off >>= 1)
                lsum[mt][r] += __shfl_xor(lsum[mt][r], off, 64);
        }

    __syncthreads();     // all waves done with Ps
    if (wave != 0) {
        float* oc = Oc + (wave - 1) * (32 * 132);
        #pragma unroll
        for (int mt = 0; mt < 2; ++mt) {
            #pragma unroll
            for (int dt = 0; dt < 8; ++dt)
                #pragma unroll
                for (int r = 0; r < 4; ++r)
                    oc[(mt * 16 + quad * 4 + r) * 132 + dt * 16 + col] = oacc[mt][dt][r];
            if (col == 0) {
                #pragma unroll
                for (int r = 0; r < 4; ++r)
                    Lc[(wave - 1) * 32 + mt * 16 + quad * 4 + r] = lsum[mt][r];
            }
        }
    }
    __syncthreads();
    if (wave == 0) {
        #pragma unroll
        for (int mt = 0; mt < 2; ++mt) {
            float inv[4];
            #pragma unroll
            for (int r = 0; r < 4; ++r) {
                float l = lsum[mt][r];
                #pragma unroll
                for (int s2 = 0; s2 < 3; ++s2)
                    l += Lc[s2 * 32 + mt * 16 + quad * 4 + r];
                inv[r] = 1.0f / l;
            }
            #pragma unroll
            for (int dt = 0; dt < 8; ++dt) {
                #pragma unroll
                for (int r = 0; r < 4; ++r) {
                    float v = oacc[mt][dt][r];
                    #pragma unroll
                    for (int s2 = 0; s2 < 3; ++s2)
                        v += Oc[s2 * (32 * 132) + (mt * 16 + quad * 4 + r) * 132 + dt * 16 + col];
                    O[(size_t)(row0 + mt * 16 + quad * 4 + r) * DIMN + head * HDIM + dt * 16 + col]
                        = to_bf16(v * inv[r]);
                }
            }
        }
    }
}

// ---------------------------------------------------------------------------
extern "C" void kernel_launch(void* const* d_in, const int* in_sizes, int n_in,
                              void* d_out, int out_size, void* d_ws, size_t ws_size,
                              hipStream_t stream)
{
    const float* x     = (const float*)d_in[0];
    const float* freqs = (const float*)d_in[1];
    const float* wq    = (const float*)d_in[2];
    const float* bq    = (const float*)d_in[3];
    const float* wk    = (const float*)d_in[4];
    const float* bk    = (const float*)d_in[5];
    const float* wv    = (const float*)d_in[6];
    const float* bv    = (const float*)d_in[7];
    const float* wo    = (const float*)d_in[8];
    const float* bo    = (const float*)d_in[9];
    const float* gq    = (const float*)d_in[10];
    const float* gk    = (const float*)d_in[11];
    const int* seq_lens   = (const int*)d_in[12];
    const int* grid_sizes = (const int*)d_in[13];
    float* out = (float*)d_out;

    const size_t NX = (size_t)SLEN * DIMN;
    const size_t NW = (size_t)DIMN * DIMN;
    short* xb  = (short*)d_ws;
    short* wqb = xb + NX;
    short* wkb = wqb + NW;
    short* wvb = wkb + NW;
    short* wob = wvb + NW;
    short* qb  = wob + NW;
    short* kb  = qb + NX;
    short* vb  = kb + NX;
    short* vp  = vb + NX;
    short* kp  = vp + NX;
    short* ob  = vb;          // vb dead after pack_v

    cast5<<<dim3(1536, 5), 256, 0, stream>>>(x, wq, wk, wv, wo,
                                             xb, wqb, wkb, wvb, wob,
                                             (int)NX, (int)NW);

    gemm_qkv<<<dim3(3 * DIMN / 128, SLEN / 128), 256, 0, stream>>>(
        xb, wqb, wkb, wvb, bq, bk, bv, qb, kb, vb);

    rms_rope_q<<<SLEN, 256, 0, stream>>>(qb, gq, freqs, grid_sizes);
    rms_rope_k_pack<<<SLEN, 256, 0, stream>>>(kb, kp, gk, freqs, grid_sizes);
    pack_v<<<dim3(NHEAD, SLEN / 64), 256, 0, stream>>>(vb, vp);

    attn_mfma5<<<dim3(SLEN / 32, NHEAD), 256, 0, stream>>>(qb, kp, vp, ob, seq_lens);

    gemm_out<<<dim3(DIMN / 128, SLEN / 128), 256, 0, stream>>>(ob, wob, bo, out);
}